// Round 15
// baseline (510.347 us; speedup 1.0000x reference)
//
#include <hip/hip_runtime.h>
#include <math.h>

typedef float  f32x4  __attribute__((ext_vector_type(4)));
typedef short  bf16x8 __attribute__((ext_vector_type(8)));

__device__ __forceinline__ unsigned short f2bf(float f) {
    union { float f; unsigned u; } v; v.f = f;
    unsigned u = v.u;
    return (unsigned short)((u + 0x7FFFu + ((u >> 16) & 1u)) >> 16);
}
__device__ __forceinline__ float bf2f(unsigned short u) {
    union { unsigned u; float f; } v; v.u = (unsigned)u << 16; return v.f;
}

#define GLOAD_LDS16(g, l)                                                      \
    __builtin_amdgcn_global_load_lds(                                          \
        (const __attribute__((address_space(1))) void*)(g),                    \
        (__attribute__((address_space(3))) void*)(l), 16, 0, 0)

// ---------------------------------------------------------------------------
// gemm4 (r12-verified best): BM=2*MR*16 x BN=4*NR*16 tile, BK=64, 8 waves,
// 2 LDS dbuf, stage-first + one barrier/K-tile, both-sides XOR swizzle
// (0 bank conflicts, verified r11/r12), setprio around MFMA cluster.
// <4,2> = 128x128 (text), <2,2> = 64x128 (image; 48KB LDS -> more blocks/CU).
// A: bf16 [M,K] lda; BT: bf16 [N,K] ldb; C: fp32 or bf16, ldc.
// Batched via blockIdx.z. K%64==0. A-staging may over-read rows past M
// (workspace buffers have slack); C-writes are guarded.
// ---------------------------------------------------------------------------
template<int MR, int NR, bool OUT_BF16, bool RELU>
__global__ __launch_bounds__(512, 4)
void gemm4_bf16(const unsigned short* __restrict__ A,
                const unsigned short* __restrict__ BT,
                const float* __restrict__ bias, void* __restrict__ Cv,
                int M, int N, int K, int lda, int ldb, int ldc,
                long long sA, long long sB, long long sC, float alpha,
                int gx, int gy)
{
    constexpr int BK = 64;
    constexpr int WM = MR * 16, WN = NR * 16;
    constexpr int BM = 2 * WM, BN = 4 * WN;
    __shared__ unsigned short Asm[2][BM * BK];
    __shared__ unsigned short Bsm[2][BN * BK];

    A  += (long long)blockIdx.z * sA;
    BT += (long long)blockIdx.z * sB;
    char* Cb = (char*)Cv + (long long)blockIdx.z * sC * (OUT_BF16 ? 2 : 4);

    // bijective XCD swizzle (m204); n-fastest within each XCD chunk
    const int nwg = gx * gy;
    int orig = blockIdx.x;
    int xcd = orig & 7, sidx = orig >> 3;
    int qq = nwg >> 3, rr = nwg & 7;
    int wg = (xcd < rr ? xcd * (qq + 1) : rr * (qq + 1) + (xcd - rr) * qq) + sidx;
    const int row0 = (wg / gx) * BM;
    const int col0 = (wg % gx) * BN;

    const int tid  = threadIdx.x;
    const int lane = tid & 63;
    const int wave = tid >> 6;
    const int wr   = wave >> 2;
    const int wc   = wave & 3;

    const int lrow = lane & 15;
    const int cgrp = lane >> 4;

    f32x4 acc[MR][NR] = {};

    // staging: 512 thr x 16B = 8 KB = 64 rows x 128 B per issue; linear LDS
    // dest, source chunk pre-swizzled: LDS physical chunk p at row r holds
    // logical chunk p^(r&7).   [both-sides swizzle, verified r11/r12]
    const int srl = tid >> 3;
    const int scl = (tid & 7) ^ (srl & 7);

    auto stage = [&](int buf, int k0) {
        #pragma unroll
        for (int is = 0; is < BM / 64; ++is)
            GLOAD_LDS16(A + (long long)(row0 + is * 64 + srl) * lda + (k0 + scl * 8),
                        &Asm[buf][is * 64 * BK + tid * 8]);
        #pragma unroll
        for (int is = 0; is < BN / 64; ++is)
            GLOAD_LDS16(BT + (long long)(col0 + is * 64 + srl) * ldb + (k0 + scl * 8),
                        &Bsm[buf][is * 64 * BK + tid * 8]);
    };

    const int nt = K / BK;
    stage(0, 0);
    __syncthreads();

    for (int t = 0; t < nt; ++t) {
        if (t + 1 < nt) stage((t + 1) & 1, (t + 1) * BK);
        const int cur = t & 1;

        bf16x8 a_[2][MR], b_[2][NR];
        #pragma unroll
        for (int kk = 0; kk < 2; ++kk) {
            #pragma unroll
            for (int mf = 0; mf < MR; ++mf) {
                int row = wr * WM + mf * 16 + lrow;
                int phys = (kk * 4 + cgrp) ^ (row & 7);
                a_[kk][mf] = *(const bf16x8*)&Asm[cur][row * BK + phys * 8];
            }
            #pragma unroll
            for (int nf = 0; nf < NR; ++nf) {
                int row = wc * WN + nf * 16 + lrow;
                int phys = (kk * 4 + cgrp) ^ (row & 7);
                b_[kk][nf] = *(const bf16x8*)&Bsm[cur][row * BK + phys * 8];
            }
        }

        __builtin_amdgcn_s_setprio(1);
        #pragma unroll
        for (int kk = 0; kk < 2; ++kk)
            #pragma unroll
            for (int mf = 0; mf < MR; ++mf)
                #pragma unroll
                for (int nf = 0; nf < NR; ++nf)
                    acc[mf][nf] = __builtin_amdgcn_mfma_f32_16x16x32_bf16(
                        a_[kk][mf], b_[kk][nf], acc[mf][nf], 0, 0, 0);
        __builtin_amdgcn_s_setprio(0);

        __syncthreads();
    }

    // C/D layout: col = lane&15, row = (lane>>4)*4 + j   [m89 verified]
    const int crow = cgrp * 4;
    const int ccol = lane & 15;
    #pragma unroll
    for (int mf = 0; mf < MR; ++mf) {
        int rbase = row0 + wr * WM + mf * 16 + crow;
        #pragma unroll
        for (int nf = 0; nf < NR; ++nf) {
            int c = col0 + wc * WN + nf * 16 + ccol;
            if (c >= N) continue;
            float bv = bias ? bias[c] : 0.f;
            #pragma unroll
            for (int j = 0; j < 4; ++j) {
                int r = rbase + j;
                if (r >= M) continue;
                float v = acc[mf][nf][j] * alpha + bv;
                if (RELU) v = fmaxf(v, 0.f);
                if (OUT_BF16)
                    ((unsigned short*)Cb)[(long long)r * ldc + c] = f2bf(v);
                else
                    ((float*)Cb)[(long long)r * ldc + c] = v;
            }
        }
    }
}

template<int MR, int NR>
static void gemm4_t(bool outBf16, bool relu,
                    const unsigned short* A, const unsigned short* BT, const float* bias,
                    void* C, int M, int N, int K, int lda, int ldb, int ldc,
                    int batch, long long sA, long long sB, long long sC,
                    float alpha, hipStream_t st)
{
    const int BM = 2 * MR * 16, BN = 4 * NR * 16;
    int gx = (N + BN - 1) / BN, gy = (M + BM - 1) / BM;
    dim3 grid(gx * gy, 1, batch);
    if (outBf16) {
        if (relu) gemm4_bf16<MR, NR, true , true ><<<grid, 512, 0, st>>>(A, BT, bias, C, M, N, K, lda, ldb, ldc, sA, sB, sC, alpha, gx, gy);
        else      gemm4_bf16<MR, NR, true , false><<<grid, 512, 0, st>>>(A, BT, bias, C, M, N, K, lda, ldb, ldc, sA, sB, sC, alpha, gx, gy);
    } else {
        if (relu) gemm4_bf16<MR, NR, false, true ><<<grid, 512, 0, st>>>(A, BT, bias, C, M, N, K, lda, ldb, ldc, sA, sB, sC, alpha, gx, gy);
        else      gemm4_bf16<MR, NR, false, false><<<grid, 512, 0, st>>>(A, BT, bias, C, M, N, K, lda, ldb, ldc, sA, sB, sC, alpha, gx, gy);
    }
}

// ---------------------------------------------------------------------------
// old m97-structure engine, kept for the small batched GEMMs (scores, PV)
// ---------------------------------------------------------------------------
template<int BM, int BN, bool OUT_BF16>
__global__ __launch_bounds__(256)
void gemm_bf16(const unsigned short* __restrict__ A,
               const unsigned short* __restrict__ BT,
               const float* __restrict__ bias, void* __restrict__ Cv,
               int M, int N, int K, int lda, int ldb, int ldc,
               long long sA, long long sB, long long sC, float alpha,
               int gx, int gy)
{
    constexpr int BK = 32;
    constexpr int WM = BM / 2, WN = BN / 2;
    constexpr int MR = WM / 16, NR = WN / 16;
    __shared__ unsigned short Asm[BM * BK];
    __shared__ unsigned short Bsm[BN * BK];

    A  += (long long)blockIdx.z * sA;
    BT += (long long)blockIdx.z * sB;
    char* Cb = (char*)Cv + (long long)blockIdx.z * sC * (OUT_BF16 ? 2 : 4);

    const int nwg = gx * gy;
    int orig = blockIdx.x;
    int xcd = orig & 7, sidx = orig >> 3;
    int qq = nwg >> 3, rr = nwg & 7;
    int wg = (xcd < rr ? xcd * (qq + 1) : rr * (qq + 1) + (xcd - rr) * qq) + sidx;
    const int row0 = (wg % gy) * BM;
    const int col0 = (wg / gy) * BN;

    const int tid  = threadIdx.x;
    const int lane = tid & 63;
    const int wave = tid >> 6;
    const int wr   = wave >> 1;
    const int wc   = wave & 1;

    const int srow = tid >> 2;
    const int skel = (tid & 3) * 8;

    f32x4 acc[MR][NR] = {};

    const int lrow = lane & 15;
    const int lk   = (lane >> 4) * 8;

    for (int k0 = 0; k0 < K; k0 += BK) {
        #pragma unroll
        for (int is = 0; is < BM / 64; ++is)
            GLOAD_LDS16(A + (long long)(row0 + is * 64 + srow) * lda + (k0 + skel),
                        &Asm[(is * 64 + srow) * BK + skel]);
        #pragma unroll
        for (int is = 0; is < BN / 64; ++is)
            GLOAD_LDS16(BT + (long long)(col0 + is * 64 + srow) * ldb + (k0 + skel),
                        &Bsm[(is * 64 + srow) * BK + skel]);
        __syncthreads();

        bf16x8 af[MR], bfr[NR];
        #pragma unroll
        for (int mf = 0; mf < MR; ++mf)
            af[mf] = *(const bf16x8*)&Asm[(wr * WM + mf * 16 + lrow) * BK + lk];
        #pragma unroll
        for (int nf = 0; nf < NR; ++nf)
            bfr[nf] = *(const bf16x8*)&Bsm[(wc * WN + nf * 16 + lrow) * BK + lk];
        #pragma unroll
        for (int mf = 0; mf < MR; ++mf)
            #pragma unroll
            for (int nf = 0; nf < NR; ++nf)
                acc[mf][nf] = __builtin_amdgcn_mfma_f32_16x16x32_bf16(
                    af[mf], bfr[nf], acc[mf][nf], 0, 0, 0);
        __syncthreads();
    }

    const int crow = (lane >> 4) * 4;
    const int ccol = lane & 15;
    #pragma unroll
    for (int mf = 0; mf < MR; ++mf) {
        int rbase = row0 + wr * WM + mf * 16 + crow;
        #pragma unroll
        for (int nf = 0; nf < NR; ++nf) {
            int c = col0 + wc * WN + nf * 16 + ccol;
            if (c >= N) continue;
            float bv = bias ? bias[c] : 0.f;
            #pragma unroll
            for (int j = 0; j < 4; ++j) {
                int r = rbase + j;
                if (r >= M) continue;
                float v = acc[mf][nf][j] * alpha + bv;
                if (OUT_BF16)
                    ((unsigned short*)Cb)[(long long)r * ldc + c] = f2bf(v);
                else
                    ((float*)Cb)[(long long)r * ldc + c] = v;
            }
        }
    }
}

template<int BM, int BN>
static void gemm_t(bool outBf16,
                   const unsigned short* A, const unsigned short* BT, const float* bias,
                   void* C, int M, int N, int K, int lda, int ldb, int ldc,
                   int batch, long long sA, long long sB, long long sC,
                   float alpha, hipStream_t st)
{
    int gx = (N + BN - 1) / BN, gy = (M + BM - 1) / BM;
    dim3 grid(gx * gy, 1, batch);
    if (outBf16)
        gemm_bf16<BM, BN, true ><<<grid, 256, 0, st>>>(A, BT, bias, C, M, N, K, lda, ldb, ldc, sA, sB, sC, alpha, gx, gy);
    else
        gemm_bf16<BM, BN, false><<<grid, 256, 0, st>>>(A, BT, bias, C, M, N, K, lda, ldb, ldc, sA, sB, sC, alpha, gx, gy);
}

// ---------------------------------------------------------------------------
// counter zeroing (graph-safe; counters self-reset but ws is poisoned 0xAA)
// ---------------------------------------------------------------------------
__global__ void zero_counters_kernel(unsigned* __restrict__ ctr)
{
    if (threadIdx.x < 16) ctr[threadIdx.x] = 0u;
}

// ---------------------------------------------------------------------------
// fused whole-norm stats over z = a + f: per-block fp64 partials + last-block
// finish (deterministic: fixed 256-thread tree over fixed partial order).
// ---------------------------------------------------------------------------
__global__ void stats_fused_kernel(const float4* __restrict__ a, const float4* __restrict__ f,
                                   double* __restrict__ part, float* __restrict__ stats,
                                   unsigned* __restrict__ counter, long long n4, double n)
{
    __shared__ double rs[256], rs2[256];
    __shared__ unsigned lastflag;
    int tid = threadIdx.x;
    long long i = (long long)blockIdx.x * blockDim.x + tid;
    long long stride = (long long)gridDim.x * blockDim.x;
    double s = 0.0, s2 = 0.0;
    for (; i < n4; i += stride) {
        float4 av = a[i], fv = f[i];
        float z0 = av.x + fv.x, z1 = av.y + fv.y, z2 = av.z + fv.z, z3 = av.w + fv.w;
        s  += (double)z0 + (double)z1 + (double)z2 + (double)z3;
        s2 += (double)z0 * z0 + (double)z1 * z1 + (double)z2 * z2 + (double)z3 * z3;
    }
    rs[tid] = s; rs2[tid] = s2; __syncthreads();
    for (int k = 128; k > 0; k >>= 1) {
        if (tid < k) { rs[tid] += rs[tid + k]; rs2[tid] += rs2[tid + k]; }
        __syncthreads();
    }
    if (tid == 0) {
        part[2 * blockIdx.x] = rs[0]; part[2 * blockIdx.x + 1] = rs2[0];
        __threadfence();
        unsigned old = atomicAdd(counter, 1u);
        lastflag = (old == gridDim.x - 1) ? 1u : 0u;
    }
    __syncthreads();
    if (lastflag) {
        __threadfence();
        int npart = gridDim.x;
        double t1 = 0.0, t2 = 0.0;
        for (int j = tid; j < npart; j += 256) { t1 += part[2 * j]; t2 += part[2 * j + 1]; }
        __syncthreads();
        rs[tid] = t1; rs2[tid] = t2; __syncthreads();
        for (int k = 128; k > 0; k >>= 1) {
            if (tid < k) { rs[tid] += rs[tid + k]; rs2[tid] += rs2[tid + k]; }
            __syncthreads();
        }
        if (tid == 0) {
            double mu  = rs[0] / n;
            double var = rs2[0] / n - mu * mu;
            stats[0] = (float)mu;
            stats[1] = (float)(1.0 / sqrt(var + 1e-6));
            *counter = 0u;
        }
    }
}

// ---------------------------------------------------------------------------
// fused split-K reduce + bias + residual + stats + last-block finish
// ---------------------------------------------------------------------------
__global__ void splitk_stats_fused_kernel(const float4* __restrict__ part,
                                          const float4* __restrict__ bias,
                                          const float4* __restrict__ x,
                                          float4* __restrict__ z,
                                          double* __restrict__ dpart,
                                          float* __restrict__ stats,
                                          unsigned* __restrict__ counter,
                                          long long n4, int N4, int nsplit,
                                          long long stride4, double n)
{
    __shared__ double rs[256], rs2[256];
    __shared__ unsigned lastflag;
    int tid = threadIdx.x;
    long long i = (long long)blockIdx.x * blockDim.x + tid;
    long long gs = (long long)gridDim.x * blockDim.x;
    double s = 0.0, s2 = 0.0;
    for (; i < n4; i += gs) {
        float4 a = part[i];
        for (int sp = 1; sp < nsplit; ++sp) {
            float4 b = part[(long long)sp * stride4 + i];
            a.x += b.x; a.y += b.y; a.z += b.z; a.w += b.w;
        }
        float4 bv = bias[(int)(i % N4)];
        float4 xv = x[i];
        a.x += bv.x + xv.x; a.y += bv.y + xv.y; a.z += bv.z + xv.z; a.w += bv.w + xv.w;
        z[i] = a;
        s  += (double)a.x + (double)a.y + (double)a.z + (double)a.w;
        s2 += (double)a.x * a.x + (double)a.y * a.y + (double)a.z * a.z + (double)a.w * a.w;
    }
    rs[tid] = s; rs2[tid] = s2; __syncthreads();
    for (int k = 128; k > 0; k >>= 1) {
        if (tid < k) { rs[tid] += rs[tid + k]; rs2[tid] += rs2[tid + k]; }
        __syncthreads();
    }
    if (tid == 0) {
        dpart[2 * blockIdx.x] = rs[0]; dpart[2 * blockIdx.x + 1] = rs2[0];
        __threadfence();
        unsigned old = atomicAdd(counter, 1u);
        lastflag = (old == gridDim.x - 1) ? 1u : 0u;
    }
    __syncthreads();
    if (lastflag) {
        __threadfence();
        int npart = gridDim.x;
        double t1 = 0.0, t2 = 0.0;
        for (int j = tid; j < npart; j += 256) { t1 += dpart[2 * j]; t2 += dpart[2 * j + 1]; }
        __syncthreads();
        rs[tid] = t1; rs2[tid] = t2; __syncthreads();
        for (int k = 128; k > 0; k >>= 1) {
            if (tid < k) { rs[tid] += rs[tid + k]; rs2[tid] += rs2[tid + k]; }
            __syncthreads();
        }
        if (tid == 0) {
            double mu  = rs[0] / n;
            double var = rs2[0] / n - mu * mu;
            stats[0] = (float)mu;
            stats[1] = (float)(1.0 / sqrt(var + 1e-6));
            *counter = 0u;
        }
    }
}

// norm apply recomputing z = a + f, bf16 out (norm1 -> y1)
__global__ void norm_apply_kernel(const float4* __restrict__ a, const float4* __restrict__ f,
                                  const float4* __restrict__ nw, const float4* __restrict__ nb,
                                  const float* __restrict__ stats, ushort4* __restrict__ out,
                                  long long n4)
{
    float mu = stats[0], rstd = stats[1];
    long long i = (long long)blockIdx.x * blockDim.x + threadIdx.x;
    long long stride = (long long)gridDim.x * blockDim.x;
    for (; i < n4; i += stride) {
        float4 av = a[i], fv = f[i], wv = nw[i], bv = nb[i];
        ushort4 o;
        o.x = f2bf((av.x + fv.x - mu) * rstd * wv.x + bv.x);
        o.y = f2bf((av.y + fv.y - mu) * rstd * wv.y + bv.y);
        o.z = f2bf((av.z + fv.z - mu) * rstd * wv.z + bv.z);
        o.w = f2bf((av.w + fv.w - mu) * rstd * wv.w + bv.w);
        out[i] = o;
    }
}

// norm apply reading z directly (z already includes residual), fp32 out
__global__ void norm_apply_z_kernel(const float4* __restrict__ z,
                                    const float4* __restrict__ nw, const float4* __restrict__ nb,
                                    const float* __restrict__ stats, float4* __restrict__ out,
                                    long long n4)
{
    float mu = stats[0], rstd = stats[1];
    long long i = (long long)blockIdx.x * blockDim.x + threadIdx.x;
    long long stride = (long long)gridDim.x * blockDim.x;
    for (; i < n4; i += stride) {
        float4 zv = z[i], wv = nw[i], bv = nb[i];
        float4 o;
        o.x = (zv.x - mu) * rstd * wv.x + bv.x;
        o.y = (zv.y - mu) * rstd * wv.y + bv.y;
        o.z = (zv.z - mu) * rstd * wv.z + bv.z;
        o.w = (zv.w - mu) * rstd * wv.w + bv.w;
        out[i] = o;
    }
}

// ---------------------------------------------------------------------------
// elementwise cast f32 -> bf16
// ---------------------------------------------------------------------------
__global__ void cast_bf16_kernel(const float4* __restrict__ in,
                                 ushort4* __restrict__ out, long long n4)
{
    long long i = (long long)blockIdx.x * blockDim.x + threadIdx.x;
    long long stride = (long long)gridDim.x * blockDim.x;
    for (; i < n4; i += stride) {
        float4 v = in[i];
        ushort4 o;
        o.x = f2bf(v.x); o.y = f2bf(v.y); o.z = f2bf(v.z); o.w = f2bf(v.w);
        out[i] = o;
    }
}

// concat bias: out = [bq | bk | bv]
__global__ void concat_bias_kernel(const float* __restrict__ bq, const float* __restrict__ bk,
                                   const float* __restrict__ bv, float* __restrict__ out, int D)
{
    int i = blockIdx.x * 256 + threadIdx.x;
    if (i < D) { out[i] = bq[i]; out[D + i] = bk[i]; out[2 * D + i] = bv[i]; }
}

// ---------------------------------------------------------------------------
// transpose + cast: src f32 [R,C] -> dst bf16 [C, Rpad]
// ---------------------------------------------------------------------------
__global__ void transpose_cast_kernel(const float* __restrict__ src,
                                      unsigned short* __restrict__ dst,
                                      int R, int C, int Rpad,
                                      long long sSrc, long long sDst)
{
    __shared__ float t[32][33];
    src += (long long)blockIdx.z * sSrc;
    dst += (long long)blockIdx.z * sDst;
    int r0 = blockIdx.x * 32, c0 = blockIdx.y * 32;
    int tx = threadIdx.x & 31, ty = threadIdx.x >> 5;
    #pragma unroll
    for (int i = 0; i < 32; i += 8) {
        int r = r0 + ty + i, c = c0 + tx;
        t[ty + i][tx] = (r < R && c < C) ? src[(long long)r * C + c] : 0.f;
    }
    __syncthreads();
    #pragma unroll
    for (int i = 0; i < 32; i += 8) {
        int c = c0 + ty + i, r = r0 + tx;
        if (c < C && r < Rpad)
            dst[(long long)c * Rpad + r] = f2bf(t[tx][ty + i]);
    }
}

// three same-shape square transposes in one launch (QKV weights), z selects
__global__ void transpose_cast3_kernel(const float* __restrict__ s0,
                                       const float* __restrict__ s1,
                                       const float* __restrict__ s2,
                                       unsigned short* __restrict__ dst, int D)
{
    __shared__ float t[32][33];
    const float* src = blockIdx.z == 0 ? s0 : (blockIdx.z == 1 ? s1 : s2);
    dst += (long long)blockIdx.z * D * D;
    int r0 = blockIdx.x * 32, c0 = blockIdx.y * 32;
    int tx = threadIdx.x & 31, ty = threadIdx.x >> 5;
    #pragma unroll
    for (int i = 0; i < 32; i += 8)
        t[ty + i][tx] = src[(long long)(r0 + ty + i) * D + (c0 + tx)];
    __syncthreads();
    #pragma unroll
    for (int i = 0; i < 32; i += 8)
        dst[(long long)(c0 + ty + i) * D + (r0 + tx)] = f2bf(t[tx][ty + i]);
}

// transpose bf16 [R,C] (row stride ldS) -> bf16 [C, Rpad]
__global__ void transpose_bf16_kernel(const unsigned short* __restrict__ src,
                                      unsigned short* __restrict__ dst,
                                      int R, int C, int Rpad, int ldS,
                                      long long sSrc, long long sDst)
{
    __shared__ unsigned short t[32][33];
    src += (long long)blockIdx.z * sSrc;
    dst += (long long)blockIdx.z * sDst;
    int r0 = blockIdx.x * 32, c0 = blockIdx.y * 32;
    int tx = threadIdx.x & 31, ty = threadIdx.x >> 5;
    #pragma unroll
    for (int i = 0; i < 32; i += 8) {
        int r = r0 + ty + i, c = c0 + tx;
        t[ty + i][tx] = (r < R && c < C) ? src[(long long)r * ldS + c] : (unsigned short)0;
    }
    __syncthreads();
    #pragma unroll
    for (int i = 0; i < 32; i += 8) {
        int c = c0 + ty + i, r = r0 + tx;
        if (c < C && r < Rpad)
            dst[(long long)c * Rpad + r] = t[tx][ty + i];
    }
}

// ---------------------------------------------------------------------------
// Ktot two-stage deterministic reduction over s (bf16 input, strided ld)
// ---------------------------------------------------------------------------
#define KTOT_NCH 16
__global__ void ktot_partial_bf16(const unsigned short* __restrict__ k,
                                  float* __restrict__ part,
                                  int B, int S, int D, int ld)
{
    int bch = blockIdx.x;
    int b  = bch / KTOT_NCH;
    int ch = bch % KTOT_NCH;
    int d  = blockIdx.y * 256 + threadIdx.x;
    if (d >= D) return;
    int len = (S + KTOT_NCH - 1) / KTOT_NCH;
    int lo = ch * len;
    int hi = lo + len < S ? lo + len : S;
    const unsigned short* kp = k + ((long long)b * S + lo) * ld + d;
    float s = 0.f;
    for (int t = lo; t < hi; ++t, kp += ld) s += bf2f(*kp);
    part[(long long)bch * D + d] = s;
}

__global__ void ktot_finish_kernel(const float* __restrict__ part,
                                   float* __restrict__ ktot, int B, int D)
{
    int idx = blockIdx.x * blockDim.x + threadIdx.x;
    if (idx >= B * D) return;
    int b = idx / D, d = idx % D;
    float s = 0.f;
    #pragma unroll
    for (int ch = 0; ch < KTOT_NCH; ++ch)
        s += part[((long long)b * KTOT_NCH + ch) * D + d];
    ktot[idx] = s;
}

// ---------------------------------------------------------------------------
// kk[b,s,d] = (Ktot[b,d] + (e-1)*window_sum) / Z_s  from bf16 k (stride ld)
// ---------------------------------------------------------------------------
__global__ void kk_bf16_kernel(const unsigned short* __restrict__ k,
                               const float* __restrict__ ktot,
                               unsigned short* __restrict__ kk,
                               int B, int S, int D, int ld)
{
    long long idx = (long long)blockIdx.x * blockDim.x + threadIdx.x;
    int D4 = D >> 2;
    long long n4 = (long long)B * S * D4;
    if (idx >= n4) return;
    int d4 = (int)(idx % D4);
    long long bs = idx / D4;
    int s = (int)(bs % S);
    int b = (int)(bs / S);
    int lo = s - 2 > 0 ? s - 2 : 0;
    int hi = s + 2 < S - 1 ? s + 2 : S - 1;
    int c = hi - lo + 1;
    const float E = 2.718281828459045f;
    float Zinv = 1.f / ((float)(S - c) + E * (float)c);

    float w0 = 0.f, w1 = 0.f, w2 = 0.f, w3 = 0.f;
    const unsigned short* kp = k + ((long long)b * S + lo) * ld + d4 * 4;
    for (int t = lo; t <= hi; ++t, kp += ld) {
        ushort4 kv = *(const ushort4*)kp;
        w0 += bf2f(kv.x); w1 += bf2f(kv.y); w2 += bf2f(kv.z); w3 += bf2f(kv.w);
    }
    float4 tot = *((const float4*)(ktot + b * D) + d4);
    ushort4 o;
    o.x = f2bf((tot.x + (E - 1.f) * w0) * Zinv);
    o.y = f2bf((tot.y + (E - 1.f) * w1) * Zinv);
    o.z = f2bf((tot.z + (E - 1.f) * w2) * Zinv);
    o.w = f2bf((tot.w + (E - 1.f) * w3) * Zinv);
    ((ushort4*)(kk + ((long long)b * S + s) * D))[d4] = o;
}

// ---------------------------------------------------------------------------
// row softmax: fp32 scores [rows][Spad] -> bf16 P, pads = 0
// ---------------------------------------------------------------------------
__global__ void softmax_rows_bf16(const float* __restrict__ sc,
                                  unsigned short* __restrict__ P, int S, int Spad)
{
    long long row = blockIdx.x;
    const float* p = sc + row * (long long)Spad;
    unsigned short* o = P + row * (long long)Spad;
    int tid = threadIdx.x;
    __shared__ float red[256];

    float m = -INFINITY;
    for (int t = tid; t < S; t += 256) m = fmaxf(m, p[t]);
    red[tid] = m; __syncthreads();
    for (int s = 128; s > 0; s >>= 1) {
        if (tid < s) red[tid] = fmaxf(red[tid], red[tid + s]);
        __syncthreads();
    }
    m = red[0];
    __syncthreads();

    float sum = 0.f;
    for (int t = tid; t < S; t += 256) sum += __expf(p[t] - m);
    red[tid] = sum; __syncthreads();
    for (int s = 128; s > 0; s >>= 1) {
        if (tid < s) red[tid] += red[tid + s];
        __syncthreads();
    }
    float inv = 1.f / red[0];
    for (int t = tid; t < Spad; t += 256)
        o[t] = (t < S) ? f2bf(__expf(p[t] - m) * inv) : (unsigned short)0;
}

// ---------------------------------------------------------------------------
// host-side orchestration
// ---------------------------------------------------------------------------
struct Bufs {
    unsigned short *xb, *qkv, *kkb, *vT, *P, *h, *WqkvT, *W1T, *W2T;
    float *f32buf, *bqkv, *ktot, *ktot_part, *stats;
    double *part;
    unsigned *ctr;
};

static void run_branch(const float* x, const float* const* w, bool big,
                       float* out, int B, int S, int D, const Bufs& wsb, hipStream_t st)
{
    const float *Wq = w[0], *bq = w[1], *Wk = w[2], *bk = w[3], *Wv = w[4], *bv = w[5];
    const float *W1 = w[6], *b1 = w[7], *W2 = w[8], *b2 = w[9], *nw = w[10], *nb = w[11];

    const int Spad = (S + 31) & ~31;
    const long long M = (long long)B * S;
    const long long n = M * D;
    const long long n4 = n / 4;
    const float inv_sqrt_d = (float)(1.0 / sqrt((double)D));
    const int D3 = 3 * D, D4 = 4 * D;
    unsigned* ctr1 = wsb.ctr + (big ? 0 : 2);
    unsigned* ctr2 = wsb.ctr + (big ? 1 : 3);

    unsigned short* y1b = wsb.kkb;           // alias: kkb dead after scores GEMM
    float* scores = (float*)wsb.h;           // alias: h free until FFN1
    float* splitbuf = (float*)wsb.qkv;       // alias: qkv+kkb+vT dead during FFN2

    // casts: x -> xb ; weights -> transposed bf16 (QKV concat), bias concat
    cast_bf16_kernel<<<1024, 256, 0, st>>>((const float4*)x, (ushort4*)wsb.xb, n4);
    transpose_cast3_kernel<<<dim3(D / 32, D / 32, 3), 256, 0, st>>>(Wq, Wk, Wv, wsb.WqkvT, D);
    transpose_cast_kernel<<<dim3((D + 31) / 32, (D4 + 31) / 32, 1), 256, 0, st>>>(W1, wsb.W1T, D, D4, D, 0, 0);
    transpose_cast_kernel<<<dim3((D4 + 31) / 32, (D + 31) / 32, 1), 256, 0, st>>>(W2, wsb.W2T, D4, D, D4, 0, 0);
    concat_bias_kernel<<<(D + 255) / 256, 256, 0, st>>>(bq, bk, bv, wsb.bqkv, D);

    // fused QKV: [M,3D] bf16
    if (big)
        gemm4_t<4, 2>(true, false, wsb.xb, wsb.WqkvT, wsb.bqkv, wsb.qkv,
                      (int)M, D3, D, D, D, D3, 1, 0, 0, 0, 1.f, st);
    else
        gemm4_t<2, 2>(true, false, wsb.xb, wsb.WqkvT, wsb.bqkv, wsb.qkv,
                      (int)M, D3, D, D, D, D3, 1, 0, 0, 0, 1.f, st);

    // kk = softmax(band mask) @ k  (analytic, bf16 k at column offset D)
    const unsigned short* kcol = wsb.qkv + D;
    ktot_partial_bf16<<<dim3(B * KTOT_NCH, (D + 255) / 256), 256, 0, st>>>(kcol, wsb.ktot_part, B, S, D, D3);
    ktot_finish_kernel<<<(B * D + 255) / 256, 256, 0, st>>>(wsb.ktot_part, wsb.ktot, B, D);
    kk_bf16_kernel<<<(int)((n4 + 255) / 256), 256, 0, st>>>(kcol, wsb.ktot, wsb.kkb, B, S, D, D3);

    // vT bf16 [B][D][Spad]  (v at column offset 2D)
    transpose_bf16_kernel<<<dim3((Spad + 31) / 32, (D + 31) / 32, B), 256, 0, st>>>(
        wsb.qkv + 2 * D, wsb.vT, S, D, Spad, D3, (long long)S * D3, (long long)D * Spad);

    // scores = q @ kk^T / sqrt(D)
    gemm_t<64, 64>(false, wsb.qkv, wsb.kkb, nullptr, scores, S, S, D, D3, D, Spad,
                   B, (long long)S * D3, (long long)S * D, (long long)S * Spad, inv_sqrt_d, st);
    softmax_rows_bf16<<<(int)M, 256, 0, st>>>(scores, wsb.P, S, Spad);

    // attn = P @ v -> f32buf
    gemm_t<128, 64>(false, wsb.P, wsb.vT, nullptr, wsb.f32buf, S, D, Spad, Spad, Spad, D,
                    B, (long long)S * Spad, (long long)D * Spad, (long long)S * D, 1.f, st);

    // norm1: y1 = whole_norm(attn + x) -> bf16 (into kkb region)
    stats_fused_kernel<<<1024, 256, 0, st>>>((const float4*)wsb.f32buf, (const float4*)x,
                                             wsb.part, wsb.stats, ctr1, n4, (double)n);
    norm_apply_kernel<<<2048, 256, 0, st>>>((const float4*)wsb.f32buf, (const float4*)x,
        (const float4*)nw, (const float4*)nb, wsb.stats, (ushort4*)y1b, n4);

    // FFN1 -> h (bf16, relu)
    if (big)
        gemm4_t<4, 2>(true, true, y1b, wsb.W1T, b1, wsb.h, (int)M, D4, D, D, D, D4, 1, 0, 0, 0, 1.f, st);
    else
        gemm4_t<2, 2>(true, true, y1b, wsb.W1T, b1, wsb.h, (int)M, D4, D, D, D, D4, 1, 0, 0, 0, 1.f, st);

    // FFN2 split-K -> partials (fp32), fused reduce+bias+residual+stats+finish
    {
        int nsplit = big ? 2 : 8;
        int Ksp = D4 / nsplit;
        if (big)
            gemm4_t<4, 2>(false, false, wsb.h, wsb.W2T, nullptr, splitbuf,
                          (int)M, D, Ksp, D4, D4, D,
                          nsplit, Ksp, Ksp, M * D, 1.f, st);
        else
            gemm4_t<2, 2>(false, false, wsb.h, wsb.W2T, nullptr, splitbuf,
                          (int)M, D, Ksp, D4, D4, D,
                          nsplit, Ksp, Ksp, M * D, 1.f, st);
        splitk_stats_fused_kernel<<<1024, 256, 0, st>>>((const float4*)splitbuf, (const float4*)b2,
                                                        (const float4*)x, (float4*)wsb.f32buf,
                                                        wsb.part, wsb.stats, ctr2,
                                                        n4, D / 4, nsplit, n4, (double)n);
        norm_apply_z_kernel<<<2048, 256, 0, st>>>((const float4*)wsb.f32buf,
            (const float4*)nw, (const float4*)nb, wsb.stats, (float4*)out, n4);
    }
}

extern "C" void kernel_launch(void* const* d_in, const int* in_sizes, int n_in,
                              void* d_out, int out_size, void* d_ws, size_t ws_size,
                              hipStream_t stream)
{
    const float* text  = (const float*)d_in[0];
    const float* image = (const float*)d_in[1];
    const float* tw[12];
    const float* iw[12];
    for (int i = 0; i < 12; ++i) tw[i] = (const float*)d_in[2 + i];
    for (int i = 0; i < 12; ++i) iw[i] = (const float*)d_in[14 + i];

    float* out_text = (float*)d_out;                 // [8,512,1024]
    float* out_img  = out_text + 8LL * 512 * 1024;   // [8,196,768]

    // workspace layout (text-branch sizes; image reuses)
    char* p = (char*)d_ws;
    auto alloc = [&](long long bytes) {
        char* r = p;
        p += (bytes + 255) & ~255LL;
        return r;
    };
    const long long MD  = 4096LL * 1024;    // B*S*D
    const long long BDS = 8LL * 1024 * 512; // B*D*Spad
    const long long SS  = 8LL * 512 * 512;  // B*S*Spad
    Bufs b;
    b.xb      = (unsigned short*)alloc(MD * 2);          // 8 MB
    b.qkv     = (unsigned short*)alloc(MD * 3 * 2);      // 24 MB (splitbuf lo)
    b.kkb     = (unsigned short*)alloc(MD * 2);          // 8 MB (y1b, splitbuf mid)
    b.vT      = (unsigned short*)alloc(BDS * 2);         // 8 MB (splitbuf hi, image)
    b.P       = (unsigned short*)alloc(SS * 2);          // 4 MB
    b.h       = (unsigned short*)alloc(MD * 4 * 2);      // 32 MB (also scores)
    b.WqkvT   = (unsigned short*)alloc(3LL * 1024 * 1024 * 2);  // 6 MB
    b.W1T     = (unsigned short*)alloc(4096LL * 1024 * 2);      // 8 MB
    b.W2T     = (unsigned short*)alloc(4096LL * 1024 * 2);      // 8 MB
    b.f32buf  = (float*)alloc(MD * 4);                   // 16 MB
    b.bqkv    = (float*)alloc(3LL * 1024 * 4);
    b.ktot    = (float*)alloc(8192LL * 4);
    b.ktot_part = (float*)alloc(8192LL * KTOT_NCH * 4);
    b.part    = (double*)alloc(2048LL * 8);
    b.stats   = (float*)alloc(256);
    b.ctr     = (unsigned*)alloc(256);

    // counters must be zero every call (ws is poisoned 0xAA before timing)
    zero_counters_kernel<<<1, 64, 0, stream>>>(b.ctr);

    run_branch(text,  tw, true,  out_text, 8, 512, 1024, b, stream);
    run_branch(image, iw, false, out_img,  8, 196, 768,  b, stream);
}

// Round 17
// 438.423 us; speedup vs baseline: 1.1641x; 1.1641x over previous
//
#include <hip/hip_runtime.h>
#include <math.h>

typedef float  f32x4  __attribute__((ext_vector_type(4)));
typedef short  bf16x8 __attribute__((ext_vector_type(8)));

__device__ __forceinline__ unsigned short f2bf(float f) {
    union { float f; unsigned u; } v; v.f = f;
    unsigned u = v.u;
    return (unsigned short)((u + 0x7FFFu + ((u >> 16) & 1u)) >> 16);
}
__device__ __forceinline__ float bf2f(unsigned short u) {
    union { unsigned u; float f; } v; v.u = (unsigned)u << 16; return v.f;
}

#define GLOAD_LDS16(g, l)                                                      \
    __builtin_amdgcn_global_load_lds(                                          \
        (const __attribute__((address_space(1))) void*)(g),                    \
        (__attribute__((address_space(3))) void*)(l), 16, 0, 0)

// ---------------------------------------------------------------------------
// gemm4 (r12-verified best): 128x128 tile (MR=4,NR=2), BK=64, 8 waves,
// 2 LDS dbuf (64 KB -> 2 blocks/CU), stage-first + one barrier/K-tile,
// both-sides XOR swizzle (0 bank conflicts, verified r11/r12), setprio.
// A: bf16 [M,K] lda; BT: bf16 [N,K] ldb; C: fp32 or bf16, ldc.
// Batched via blockIdx.z. K%64==0. A-staging may over-read rows past M
// (workspace buffers have slack); C-writes are guarded.
// ---------------------------------------------------------------------------
template<int MR, int NR, bool OUT_BF16, bool RELU>
__global__ __launch_bounds__(512, 4)
void gemm4_bf16(const unsigned short* __restrict__ A,
                const unsigned short* __restrict__ BT,
                const float* __restrict__ bias, void* __restrict__ Cv,
                int M, int N, int K, int lda, int ldb, int ldc,
                long long sA, long long sB, long long sC, float alpha,
                int gx, int gy)
{
    constexpr int BK = 64;
    constexpr int WM = MR * 16, WN = NR * 16;
    constexpr int BM = 2 * WM, BN = 4 * WN;
    __shared__ unsigned short Asm[2][BM * BK];
    __shared__ unsigned short Bsm[2][BN * BK];

    A  += (long long)blockIdx.z * sA;
    BT += (long long)blockIdx.z * sB;
    char* Cb = (char*)Cv + (long long)blockIdx.z * sC * (OUT_BF16 ? 2 : 4);

    // bijective XCD swizzle (m204); n-fastest within each XCD chunk
    const int nwg = gx * gy;
    int orig = blockIdx.x;
    int xcd = orig & 7, sidx = orig >> 3;
    int qq = nwg >> 3, rr = nwg & 7;
    int wg = (xcd < rr ? xcd * (qq + 1) : rr * (qq + 1) + (xcd - rr) * qq) + sidx;
    const int row0 = (wg / gx) * BM;
    const int col0 = (wg % gx) * BN;

    const int tid  = threadIdx.x;
    const int lane = tid & 63;
    const int wave = tid >> 6;
    const int wr   = wave >> 2;
    const int wc   = wave & 3;

    const int lrow = lane & 15;
    const int cgrp = lane >> 4;

    f32x4 acc[MR][NR] = {};

    // staging: 512 thr x 16B = 8 KB = 64 rows x 128 B per issue; linear LDS
    // dest, source chunk pre-swizzled: LDS physical chunk p at row r holds
    // logical chunk p^(r&7).   [both-sides swizzle, verified r11/r12]
    const int srl = tid >> 3;
    const int scl = (tid & 7) ^ (srl & 7);

    auto stage = [&](int buf, int k0) {
        #pragma unroll
        for (int is = 0; is < BM / 64; ++is)
            GLOAD_LDS16(A + (long long)(row0 + is * 64 + srl) * lda + (k0 + scl * 8),
                        &Asm[buf][is * 64 * BK + tid * 8]);
        #pragma unroll
        for (int is = 0; is < BN / 64; ++is)
            GLOAD_LDS16(BT + (long long)(col0 + is * 64 + srl) * ldb + (k0 + scl * 8),
                        &Bsm[buf][is * 64 * BK + tid * 8]);
    };

    const int nt = K / BK;
    stage(0, 0);
    __syncthreads();

    for (int t = 0; t < nt; ++t) {
        if (t + 1 < nt) stage((t + 1) & 1, (t + 1) * BK);
        const int cur = t & 1;

        bf16x8 a_[2][MR], b_[2][NR];
        #pragma unroll
        for (int kk = 0; kk < 2; ++kk) {
            #pragma unroll
            for (int mf = 0; mf < MR; ++mf) {
                int row = wr * WM + mf * 16 + lrow;
                int phys = (kk * 4 + cgrp) ^ (row & 7);
                a_[kk][mf] = *(const bf16x8*)&Asm[cur][row * BK + phys * 8];
            }
            #pragma unroll
            for (int nf = 0; nf < NR; ++nf) {
                int row = wc * WN + nf * 16 + lrow;
                int phys = (kk * 4 + cgrp) ^ (row & 7);
                b_[kk][nf] = *(const bf16x8*)&Bsm[cur][row * BK + phys * 8];
            }
        }

        __builtin_amdgcn_s_setprio(1);
        #pragma unroll
        for (int kk = 0; kk < 2; ++kk)
            #pragma unroll
            for (int mf = 0; mf < MR; ++mf)
                #pragma unroll
                for (int nf = 0; nf < NR; ++nf)
                    acc[mf][nf] = __builtin_amdgcn_mfma_f32_16x16x32_bf16(
                        a_[kk][mf], b_[kk][nf], acc[mf][nf], 0, 0, 0);
        __builtin_amdgcn_s_setprio(0);

        __syncthreads();
    }

    // C/D layout: col = lane&15, row = (lane>>4)*4 + j   [m89 verified]
    const int crow = cgrp * 4;
    const int ccol = lane & 15;
    #pragma unroll
    for (int mf = 0; mf < MR; ++mf) {
        int rbase = row0 + wr * WM + mf * 16 + crow;
        #pragma unroll
        for (int nf = 0; nf < NR; ++nf) {
            int c = col0 + wc * WN + nf * 16 + ccol;
            if (c >= N) continue;
            float bv = bias ? bias[c] : 0.f;
            #pragma unroll
            for (int j = 0; j < 4; ++j) {
                int r = rbase + j;
                if (r >= M) continue;
                float v = acc[mf][nf][j] * alpha + bv;
                if (RELU) v = fmaxf(v, 0.f);
                if (OUT_BF16)
                    ((unsigned short*)Cb)[(long long)r * ldc + c] = f2bf(v);
                else
                    ((float*)Cb)[(long long)r * ldc + c] = v;
            }
        }
    }
}

template<int MR, int NR>
static void gemm4_t(bool outBf16, bool relu,
                    const unsigned short* A, const unsigned short* BT, const float* bias,
                    void* C, int M, int N, int K, int lda, int ldb, int ldc,
                    int batch, long long sA, long long sB, long long sC,
                    float alpha, hipStream_t st)
{
    const int BM = 2 * MR * 16, BN = 4 * NR * 16;
    int gx = (N + BN - 1) / BN, gy = (M + BM - 1) / BM;
    dim3 grid(gx * gy, 1, batch);
    if (outBf16) {
        if (relu) gemm4_bf16<MR, NR, true , true ><<<grid, 512, 0, st>>>(A, BT, bias, C, M, N, K, lda, ldb, ldc, sA, sB, sC, alpha, gx, gy);
        else      gemm4_bf16<MR, NR, true , false><<<grid, 512, 0, st>>>(A, BT, bias, C, M, N, K, lda, ldb, ldc, sA, sB, sC, alpha, gx, gy);
    } else {
        if (relu) gemm4_bf16<MR, NR, false, true ><<<grid, 512, 0, st>>>(A, BT, bias, C, M, N, K, lda, ldb, ldc, sA, sB, sC, alpha, gx, gy);
        else      gemm4_bf16<MR, NR, false, false><<<grid, 512, 0, st>>>(A, BT, bias, C, M, N, K, lda, ldb, ldc, sA, sB, sC, alpha, gx, gy);
    }
}

// ---------------------------------------------------------------------------
// old m97-structure engine, kept for the small batched GEMMs (scores, PV)
// ---------------------------------------------------------------------------
template<int BM, int BN, bool OUT_BF16>
__global__ __launch_bounds__(256)
void gemm_bf16(const unsigned short* __restrict__ A,
               const unsigned short* __restrict__ BT,
               const float* __restrict__ bias, void* __restrict__ Cv,
               int M, int N, int K, int lda, int ldb, int ldc,
               long long sA, long long sB, long long sC, float alpha,
               int gx, int gy)
{
    constexpr int BK = 32;
    constexpr int WM = BM / 2, WN = BN / 2;
    constexpr int MR = WM / 16, NR = WN / 16;
    __shared__ unsigned short Asm[BM * BK];
    __shared__ unsigned short Bsm[BN * BK];

    A  += (long long)blockIdx.z * sA;
    BT += (long long)blockIdx.z * sB;
    char* Cb = (char*)Cv + (long long)blockIdx.z * sC * (OUT_BF16 ? 2 : 4);

    const int nwg = gx * gy;
    int orig = blockIdx.x;
    int xcd = orig & 7, sidx = orig >> 3;
    int qq = nwg >> 3, rr = nwg & 7;
    int wg = (xcd < rr ? xcd * (qq + 1) : rr * (qq + 1) + (xcd - rr) * qq) + sidx;
    const int row0 = (wg % gy) * BM;
    const int col0 = (wg / gy) * BN;

    const int tid  = threadIdx.x;
    const int lane = tid & 63;
    const int wave = tid >> 6;
    const int wr   = wave >> 1;
    const int wc   = wave & 1;

    const int srow = tid >> 2;
    const int skel = (tid & 3) * 8;

    f32x4 acc[MR][NR] = {};

    const int lrow = lane & 15;
    const int lk   = (lane >> 4) * 8;

    for (int k0 = 0; k0 < K; k0 += BK) {
        #pragma unroll
        for (int is = 0; is < BM / 64; ++is)
            GLOAD_LDS16(A + (long long)(row0 + is * 64 + srow) * lda + (k0 + skel),
                        &Asm[(is * 64 + srow) * BK + skel]);
        #pragma unroll
        for (int is = 0; is < BN / 64; ++is)
            GLOAD_LDS16(BT + (long long)(col0 + is * 64 + srow) * ldb + (k0 + skel),
                        &Bsm[(is * 64 + srow) * BK + skel]);
        __syncthreads();

        bf16x8 af[MR], bfr[NR];
        #pragma unroll
        for (int mf = 0; mf < MR; ++mf)
            af[mf] = *(const bf16x8*)&Asm[(wr * WM + mf * 16 + lrow) * BK + lk];
        #pragma unroll
        for (int nf = 0; nf < NR; ++nf)
            bfr[nf] = *(const bf16x8*)&Bsm[(wc * WN + nf * 16 + lrow) * BK + lk];
        #pragma unroll
        for (int mf = 0; mf < MR; ++mf)
            #pragma unroll
            for (int nf = 0; nf < NR; ++nf)
                acc[mf][nf] = __builtin_amdgcn_mfma_f32_16x16x32_bf16(
                    af[mf], bfr[nf], acc[mf][nf], 0, 0, 0);
        __syncthreads();
    }

    const int crow = (lane >> 4) * 4;
    const int ccol = lane & 15;
    #pragma unroll
    for (int mf = 0; mf < MR; ++mf) {
        int rbase = row0 + wr * WM + mf * 16 + crow;
        #pragma unroll
        for (int nf = 0; nf < NR; ++nf) {
            int c = col0 + wc * WN + nf * 16 + ccol;
            if (c >= N) continue;
            float bv = bias ? bias[c] : 0.f;
            #pragma unroll
            for (int j = 0; j < 4; ++j) {
                int r = rbase + j;
                if (r >= M) continue;
                float v = acc[mf][nf][j] * alpha + bv;
                if (OUT_BF16)
                    ((unsigned short*)Cb)[(long long)r * ldc + c] = f2bf(v);
                else
                    ((float*)Cb)[(long long)r * ldc + c] = v;
            }
        }
    }
}

template<int BM, int BN>
static void gemm_t(bool outBf16,
                   const unsigned short* A, const unsigned short* BT, const float* bias,
                   void* C, int M, int N, int K, int lda, int ldb, int ldc,
                   int batch, long long sA, long long sB, long long sC,
                   float alpha, hipStream_t st)
{
    int gx = (N + BN - 1) / BN, gy = (M + BM - 1) / BM;
    dim3 grid(gx * gy, 1, batch);
    if (outBf16)
        gemm_bf16<BM, BN, true ><<<grid, 256, 0, st>>>(A, BT, bias, C, M, N, K, lda, ldb, ldc, sA, sB, sC, alpha, gx, gy);
    else
        gemm_bf16<BM, BN, false><<<grid, 256, 0, st>>>(A, BT, bias, C, M, N, K, lda, ldb, ldc, sA, sB, sC, alpha, gx, gy);
}

// ---------------------------------------------------------------------------
// split-K reduce + bias + residual(x) + whole-norm stats (r12-proven,
// two-kernel chain: NO inter-block communication, deterministic)
// ---------------------------------------------------------------------------
__global__ void splitk_stats_kernel(const float4* __restrict__ part,
                                    const float4* __restrict__ bias,
                                    const float4* __restrict__ x,
                                    float4* __restrict__ z,
                                    double* __restrict__ dpart,
                                    long long n4, int N4, int nsplit, long long stride4)
{
    __shared__ double rs[256], rs2[256];
    int tid = threadIdx.x;
    long long i = (long long)blockIdx.x * blockDim.x + tid;
    long long gs = (long long)gridDim.x * blockDim.x;
    double s = 0.0, s2 = 0.0;
    for (; i < n4; i += gs) {
        float4 a = part[i];
        for (int sp = 1; sp < nsplit; ++sp) {
            float4 b = part[(long long)sp * stride4 + i];
            a.x += b.x; a.y += b.y; a.z += b.z; a.w += b.w;
        }
        float4 bv = bias[(int)(i % N4)];
        float4 xv = x[i];
        a.x += bv.x + xv.x; a.y += bv.y + xv.y; a.z += bv.z + xv.z; a.w += bv.w + xv.w;
        z[i] = a;
        s  += (double)a.x + (double)a.y + (double)a.z + (double)a.w;
        s2 += (double)a.x * a.x + (double)a.y * a.y + (double)a.z * a.z + (double)a.w * a.w;
    }
    rs[tid] = s; rs2[tid] = s2; __syncthreads();
    for (int k = 128; k > 0; k >>= 1) {
        if (tid < k) { rs[tid] += rs[tid + k]; rs2[tid] += rs2[tid + k]; }
        __syncthreads();
    }
    if (tid == 0) { dpart[2 * blockIdx.x] = rs[0]; dpart[2 * blockIdx.x + 1] = rs2[0]; }
}

__global__ void stats_kernel(const float4* __restrict__ a, const float4* __restrict__ f,
                             double* __restrict__ part, long long n4)
{
    __shared__ double rs[256], rs2[256];
    int tid = threadIdx.x;
    long long i = (long long)blockIdx.x * blockDim.x + tid;
    long long stride = (long long)gridDim.x * blockDim.x;
    double s = 0.0, s2 = 0.0;
    for (; i < n4; i += stride) {
        float4 av = a[i], fv = f[i];
        float z0 = av.x + fv.x, z1 = av.y + fv.y, z2 = av.z + fv.z, z3 = av.w + fv.w;
        s  += (double)z0 + (double)z1 + (double)z2 + (double)z3;
        s2 += (double)z0 * z0 + (double)z1 * z1 + (double)z2 * z2 + (double)z3 * z3;
    }
    rs[tid] = s; rs2[tid] = s2; __syncthreads();
    for (int k = 128; k > 0; k >>= 1) {
        if (tid < k) { rs[tid] += rs[tid + k]; rs2[tid] += rs2[tid + k]; }
        __syncthreads();
    }
    if (tid == 0) { part[2 * blockIdx.x] = rs[0]; part[2 * blockIdx.x + 1] = rs2[0]; }
}

__global__ void finish_stats(const double* __restrict__ part, int npart,
                             float* __restrict__ stats, double n)
{
    __shared__ double rs[256], rs2[256];
    int tid = threadIdx.x;
    double s = 0.0, s2 = 0.0;
    for (int i = tid; i < npart; i += 256) { s += part[2 * i]; s2 += part[2 * i + 1]; }
    rs[tid] = s; rs2[tid] = s2; __syncthreads();
    for (int k = 128; k > 0; k >>= 1) {
        if (tid < k) { rs[tid] += rs[tid + k]; rs2[tid] += rs2[tid + k]; }
        __syncthreads();
    }
    if (tid == 0) {
        double mu  = rs[0] / n;
        double var = rs2[0] / n - mu * mu;
        stats[0] = (float)mu;
        stats[1] = (float)(1.0 / sqrt(var + 1e-6));
    }
}

// norm apply recomputing z = a + f, bf16 out (norm1 -> y1)
__global__ void norm_apply_kernel(const float4* __restrict__ a, const float4* __restrict__ f,
                                  const float4* __restrict__ nw, const float4* __restrict__ nb,
                                  const float* __restrict__ stats, ushort4* __restrict__ out,
                                  long long n4)
{
    float mu = stats[0], rstd = stats[1];
    long long i = (long long)blockIdx.x * blockDim.x + threadIdx.x;
    long long stride = (long long)gridDim.x * blockDim.x;
    for (; i < n4; i += stride) {
        float4 av = a[i], fv = f[i], wv = nw[i], bv = nb[i];
        ushort4 o;
        o.x = f2bf((av.x + fv.x - mu) * rstd * wv.x + bv.x);
        o.y = f2bf((av.y + fv.y - mu) * rstd * wv.y + bv.y);
        o.z = f2bf((av.z + fv.z - mu) * rstd * wv.z + bv.z);
        o.w = f2bf((av.w + fv.w - mu) * rstd * wv.w + bv.w);
        out[i] = o;
    }
}

// norm apply reading z directly (z already includes residual), fp32 out
__global__ void norm_apply_z_kernel(const float4* __restrict__ z,
                                    const float4* __restrict__ nw, const float4* __restrict__ nb,
                                    const float* __restrict__ stats, float4* __restrict__ out,
                                    long long n4)
{
    float mu = stats[0], rstd = stats[1];
    long long i = (long long)blockIdx.x * blockDim.x + threadIdx.x;
    long long stride = (long long)gridDim.x * blockDim.x;
    for (; i < n4; i += stride) {
        float4 zv = z[i], wv = nw[i], bv = nb[i];
        float4 o;
        o.x = (zv.x - mu) * rstd * wv.x + bv.x;
        o.y = (zv.y - mu) * rstd * wv.y + bv.y;
        o.z = (zv.z - mu) * rstd * wv.z + bv.z;
        o.w = (zv.w - mu) * rstd * wv.w + bv.w;
        out[i] = o;
    }
}

// ---------------------------------------------------------------------------
// elementwise cast f32 -> bf16
// ---------------------------------------------------------------------------
__global__ void cast_bf16_kernel(const float4* __restrict__ in,
                                 ushort4* __restrict__ out, long long n4)
{
    long long i = (long long)blockIdx.x * blockDim.x + threadIdx.x;
    long long stride = (long long)gridDim.x * blockDim.x;
    for (; i < n4; i += stride) {
        float4 v = in[i];
        ushort4 o;
        o.x = f2bf(v.x); o.y = f2bf(v.y); o.z = f2bf(v.z); o.w = f2bf(v.w);
        out[i] = o;
    }
}

// concat bias: out = [bq | bk | bv]  (pure data-parallel, no cross-block dep)
__global__ void concat_bias_kernel(const float* __restrict__ bq, const float* __restrict__ bk,
                                   const float* __restrict__ bv, float* __restrict__ out, int D)
{
    int i = blockIdx.x * 256 + threadIdx.x;
    if (i < D) { out[i] = bq[i]; out[D + i] = bk[i]; out[2 * D + i] = bv[i]; }
}

// ---------------------------------------------------------------------------
// transpose + cast: src f32 [R,C] -> dst bf16 [C, Rpad]
// ---------------------------------------------------------------------------
__global__ void transpose_cast_kernel(const float* __restrict__ src,
                                      unsigned short* __restrict__ dst,
                                      int R, int C, int Rpad,
                                      long long sSrc, long long sDst)
{
    __shared__ float t[32][33];
    src += (long long)blockIdx.z * sSrc;
    dst += (long long)blockIdx.z * sDst;
    int r0 = blockIdx.x * 32, c0 = blockIdx.y * 32;
    int tx = threadIdx.x & 31, ty = threadIdx.x >> 5;
    #pragma unroll
    for (int i = 0; i < 32; i += 8) {
        int r = r0 + ty + i, c = c0 + tx;
        t[ty + i][tx] = (r < R && c < C) ? src[(long long)r * C + c] : 0.f;
    }
    __syncthreads();
    #pragma unroll
    for (int i = 0; i < 32; i += 8) {
        int c = c0 + ty + i, r = r0 + tx;
        if (c < C && r < Rpad)
            dst[(long long)c * Rpad + r] = f2bf(t[tx][ty + i]);
    }
}

// three same-shape square transposes in one launch (QKV weights), z selects
__global__ void transpose_cast3_kernel(const float* __restrict__ s0,
                                       const float* __restrict__ s1,
                                       const float* __restrict__ s2,
                                       unsigned short* __restrict__ dst, int D)
{
    __shared__ float t[32][33];
    const float* src = blockIdx.z == 0 ? s0 : (blockIdx.z == 1 ? s1 : s2);
    dst += (long long)blockIdx.z * D * D;
    int r0 = blockIdx.x * 32, c0 = blockIdx.y * 32;
    int tx = threadIdx.x & 31, ty = threadIdx.x >> 5;
    #pragma unroll
    for (int i = 0; i < 32; i += 8)
        t[ty + i][tx] = src[(long long)(r0 + ty + i) * D + (c0 + tx)];
    __syncthreads();
    #pragma unroll
    for (int i = 0; i < 32; i += 8)
        dst[(long long)(c0 + ty + i) * D + (r0 + tx)] = f2bf(t[tx][ty + i]);
}

// transpose bf16 [R,C] (row stride ldS) -> bf16 [C, Rpad]
__global__ void transpose_bf16_kernel(const unsigned short* __restrict__ src,
                                      unsigned short* __restrict__ dst,
                                      int R, int C, int Rpad, int ldS,
                                      long long sSrc, long long sDst)
{
    __shared__ unsigned short t[32][33];
    src += (long long)blockIdx.z * sSrc;
    dst += (long long)blockIdx.z * sDst;
    int r0 = blockIdx.x * 32, c0 = blockIdx.y * 32;
    int tx = threadIdx.x & 31, ty = threadIdx.x >> 5;
    #pragma unroll
    for (int i = 0; i < 32; i += 8) {
        int r = r0 + ty + i, c = c0 + tx;
        t[ty + i][tx] = (r < R && c < C) ? src[(long long)r * ldS + c] : (unsigned short)0;
    }
    __syncthreads();
    #pragma unroll
    for (int i = 0; i < 32; i += 8) {
        int c = c0 + ty + i, r = r0 + tx;
        if (c < C && r < Rpad)
            dst[(long long)c * Rpad + r] = t[tx][ty + i];
    }
}

// ---------------------------------------------------------------------------
// Ktot two-stage deterministic reduction over s (bf16 input, strided ld)
// ---------------------------------------------------------------------------
#define KTOT_NCH 16
__global__ void ktot_partial_bf16(const unsigned short* __restrict__ k,
                                  float* __restrict__ part,
                                  int B, int S, int D, int ld)
{
    int bch = blockIdx.x;
    int b  = bch / KTOT_NCH;
    int ch = bch % KTOT_NCH;
    int d  = blockIdx.y * 256 + threadIdx.x;
    if (d >= D) return;
    int len = (S + KTOT_NCH - 1) / KTOT_NCH;
    int lo = ch * len;
    int hi = lo + len < S ? lo + len : S;
    const unsigned short* kp = k + ((long long)b * S + lo) * ld + d;
    float s = 0.f;
    for (int t = lo; t < hi; ++t, kp += ld) s += bf2f(*kp);
    part[(long long)bch * D + d] = s;
}

__global__ void ktot_finish_kernel(const float* __restrict__ part,
                                   float* __restrict__ ktot, int B, int D)
{
    int idx = blockIdx.x * blockDim.x + threadIdx.x;
    if (idx >= B * D) return;
    int b = idx / D, d = idx % D;
    float s = 0.f;
    #pragma unroll
    for (int ch = 0; ch < KTOT_NCH; ++ch)
        s += part[((long long)b * KTOT_NCH + ch) * D + d];
    ktot[idx] = s;
}

// ---------------------------------------------------------------------------
// kk[b,s,d] = (Ktot[b,d] + (e-1)*window_sum) / Z_s  from bf16 k (stride ld)
// ---------------------------------------------------------------------------
__global__ void kk_bf16_kernel(const unsigned short* __restrict__ k,
                               const float* __restrict__ ktot,
                               unsigned short* __restrict__ kk,
                               int B, int S, int D, int ld)
{
    long long idx = (long long)blockIdx.x * blockDim.x + threadIdx.x;
    int D4 = D >> 2;
    long long n4 = (long long)B * S * D4;
    if (idx >= n4) return;
    int d4 = (int)(idx % D4);
    long long bs = idx / D4;
    int s = (int)(bs % S);
    int b = (int)(bs / S);
    int lo = s - 2 > 0 ? s - 2 : 0;
    int hi = s + 2 < S - 1 ? s + 2 : S - 1;
    int c = hi - lo + 1;
    const float E = 2.718281828459045f;
    float Zinv = 1.f / ((float)(S - c) + E * (float)c);

    float w0 = 0.f, w1 = 0.f, w2 = 0.f, w3 = 0.f;
    const unsigned short* kp = k + ((long long)b * S + lo) * ld + d4 * 4;
    for (int t = lo; t <= hi; ++t, kp += ld) {
        ushort4 kv = *(const ushort4*)kp;
        w0 += bf2f(kv.x); w1 += bf2f(kv.y); w2 += bf2f(kv.z); w3 += bf2f(kv.w);
    }
    float4 tot = *((const float4*)(ktot + b * D) + d4);
    ushort4 o;
    o.x = f2bf((tot.x + (E - 1.f) * w0) * Zinv);
    o.y = f2bf((tot.y + (E - 1.f) * w1) * Zinv);
    o.z = f2bf((tot.z + (E - 1.f) * w2) * Zinv);
    o.w = f2bf((tot.w + (E - 1.f) * w3) * Zinv);
    ((ushort4*)(kk + ((long long)b * S + s) * D))[d4] = o;
}

// ---------------------------------------------------------------------------
// row softmax: fp32 scores [rows][Spad] -> bf16 P, pads = 0
// ---------------------------------------------------------------------------
__global__ void softmax_rows_bf16(const float* __restrict__ sc,
                                  unsigned short* __restrict__ P, int S, int Spad)
{
    long long row = blockIdx.x;
    const float* p = sc + row * (long long)Spad;
    unsigned short* o = P + row * (long long)Spad;
    int tid = threadIdx.x;
    __shared__ float red[256];

    float m = -INFINITY;
    for (int t = tid; t < S; t += 256) m = fmaxf(m, p[t]);
    red[tid] = m; __syncthreads();
    for (int s = 128; s > 0; s >>= 1) {
        if (tid < s) red[tid] = fmaxf(red[tid], red[tid + s]);
        __syncthreads();
    }
    m = red[0];
    __syncthreads();

    float sum = 0.f;
    for (int t = tid; t < S; t += 256) sum += __expf(p[t] - m);
    red[tid] = sum; __syncthreads();
    for (int s = 128; s > 0; s >>= 1) {
        if (tid < s) red[tid] += red[tid + s];
        __syncthreads();
    }
    float inv = 1.f / red[0];
    for (int t = tid; t < Spad; t += 256)
        o[t] = (t < S) ? f2bf(__expf(p[t] - m) * inv) : (unsigned short)0;
}

// ---------------------------------------------------------------------------
// host-side orchestration
// ---------------------------------------------------------------------------
struct Bufs {
    unsigned short *xb, *qkv, *kkb, *vT, *P, *h, *WqkvT, *W1T, *W2T;
    float *f32buf, *bqkv, *ktot, *ktot_part, *stats;
    double *part;
};

static void run_branch(const float* x, const float* const* w, bool big,
                       float* out, int B, int S, int D, const Bufs& wsb, hipStream_t st)
{
    const float *Wq = w[0], *bq = w[1], *Wk = w[2], *bk = w[3], *Wv = w[4], *bv = w[5];
    const float *W1 = w[6], *b1 = w[7], *W2 = w[8], *b2 = w[9], *nw = w[10], *nb = w[11];

    const int Spad = (S + 31) & ~31;
    const long long M = (long long)B * S;
    const long long n = M * D;
    const long long n4 = n / 4;
    const float inv_sqrt_d = (float)(1.0 / sqrt((double)D));
    const int D3 = 3 * D, D4 = 4 * D;

    unsigned short* y1b = wsb.kkb;           // alias: kkb dead after scores GEMM
    float* scores = (float*)wsb.h;           // alias: h free until FFN1
    float* splitbuf = (float*)wsb.qkv;       // alias: qkv+kkb+vT dead during FFN2

    // casts: x -> xb ; weights -> transposed bf16 (QKV concat), bias concat
    cast_bf16_kernel<<<1024, 256, 0, st>>>((const float4*)x, (ushort4*)wsb.xb, n4);
    transpose_cast3_kernel<<<dim3(D / 32, D / 32, 3), 256, 0, st>>>(Wq, Wk, Wv, wsb.WqkvT, D);
    transpose_cast_kernel<<<dim3((D + 31) / 32, (D4 + 31) / 32, 1), 256, 0, st>>>(W1, wsb.W1T, D, D4, D, 0, 0);
    transpose_cast_kernel<<<dim3((D4 + 31) / 32, (D + 31) / 32, 1), 256, 0, st>>>(W2, wsb.W2T, D4, D, D4, 0, 0);
    concat_bias_kernel<<<(D + 255) / 256, 256, 0, st>>>(bq, bk, bv, wsb.bqkv, D);

    // fused QKV: [M,3D] bf16 (gemm4 128x128)
    gemm4_t<4, 2>(true, false, wsb.xb, wsb.WqkvT, wsb.bqkv, wsb.qkv,
                  (int)M, D3, D, D, D, D3, 1, 0, 0, 0, 1.f, st);

    // kk = softmax(band mask) @ k  (analytic, bf16 k at column offset D)
    const unsigned short* kcol = wsb.qkv + D;
    ktot_partial_bf16<<<dim3(B * KTOT_NCH, (D + 255) / 256), 256, 0, st>>>(kcol, wsb.ktot_part, B, S, D, D3);
    ktot_finish_kernel<<<(B * D + 255) / 256, 256, 0, st>>>(wsb.ktot_part, wsb.ktot, B, D);
    kk_bf16_kernel<<<(int)((n4 + 255) / 256), 256, 0, st>>>(kcol, wsb.ktot, wsb.kkb, B, S, D, D3);

    // vT bf16 [B][D][Spad]  (v at column offset 2D)
    transpose_bf16_kernel<<<dim3((Spad + 31) / 32, (D + 31) / 32, B), 256, 0, st>>>(
        wsb.qkv + 2 * D, wsb.vT, S, D, Spad, D3, (long long)S * D3, (long long)D * Spad);

    // scores = q @ kk^T / sqrt(D)
    gemm_t<64, 64>(false, wsb.qkv, wsb.kkb, nullptr, scores, S, S, D, D3, D, Spad,
                   B, (long long)S * D3, (long long)S * D, (long long)S * Spad, inv_sqrt_d, st);
    softmax_rows_bf16<<<(int)M, 256, 0, st>>>(scores, wsb.P, S, Spad);

    // attn = P @ v -> f32buf
    gemm_t<128, 64>(false, wsb.P, wsb.vT, nullptr, wsb.f32buf, S, D, Spad, Spad, Spad, D,
                    B, (long long)S * Spad, (long long)D * Spad, (long long)S * D, 1.f, st);

    // norm1: y1 = whole_norm(attn + x) -> bf16 (into kkb region)
    stats_kernel<<<1024, 256, 0, st>>>((const float4*)wsb.f32buf, (const float4*)x, wsb.part, n4);
    finish_stats<<<1, 256, 0, st>>>(wsb.part, 1024, wsb.stats, (double)n);
    norm_apply_kernel<<<2048, 256, 0, st>>>((const float4*)wsb.f32buf, (const float4*)x,
        (const float4*)nw, (const float4*)nb, wsb.stats, (ushort4*)y1b, n4);

    // FFN1 -> h (bf16, relu), gemm4 128x128
    gemm4_t<4, 2>(true, true, y1b, wsb.W1T, b1, wsb.h, (int)M, D4, D, D, D, D4, 1, 0, 0, 0, 1.f, st);

    // FFN2 split-K -> partials (fp32), reduce+bias+residual+stats, finish, apply
    {
        int nsplit = big ? 2 : 8;
        int Ksp = D4 / nsplit;
        gemm4_t<4, 2>(false, false, wsb.h, wsb.W2T, nullptr, splitbuf,
                      (int)M, D, Ksp, D4, D4, D,
                      nsplit, Ksp, Ksp, M * D, 1.f, st);
        splitk_stats_kernel<<<1024, 256, 0, st>>>((const float4*)splitbuf, (const float4*)b2,
                                                  (const float4*)x, (float4*)wsb.f32buf,
                                                  wsb.part, n4, D / 4, nsplit, n4);
        finish_stats<<<1, 256, 0, st>>>(wsb.part, 1024, wsb.stats, (double)n);
        norm_apply_z_kernel<<<2048, 256, 0, st>>>((const float4*)wsb.f32buf,
            (const float4*)nw, (const float4*)nb, wsb.stats, (float4*)out, n4);
    }
}

extern "C" void kernel_launch(void* const* d_in, const int* in_sizes, int n_in,
                              void* d_out, int out_size, void* d_ws, size_t ws_size,
                              hipStream_t stream)
{
    const float* text  = (const float*)d_in[0];
    const float* image = (const float*)d_in[1];
    const float* tw[12];
    const float* iw[12];
    for (int i = 0; i < 12; ++i) tw[i] = (const float*)d_in[2 + i];
    for (int i = 0; i < 12; ++i) iw[i] = (const float*)d_in[14 + i];

    float* out_text = (float*)d_out;                 // [8,512,1024]
    float* out_img  = out_text + 8LL * 512 * 1024;   // [8,196,768]

    // workspace layout (text-branch sizes; image reuses)
    char* p = (char*)d_ws;
    auto alloc = [&](long long bytes) {
        char* r = p;
        p += (bytes + 255) & ~255LL;
        return r;
    };
    const long long MD  = 4096LL * 1024;    // B*S*D
    const long long BDS = 8LL * 1024 * 512; // B*D*Spad
    const long long SS  = 8LL * 512 * 512;  // B*S*Spad
    Bufs b;
    b.xb      = (unsigned short*)alloc(MD * 2);          // 8 MB
    b.qkv     = (unsigned short*)alloc(MD * 3 * 2);      // 24 MB (splitbuf lo)
    b.kkb     = (unsigned short*)alloc(MD * 2);          // 8 MB (y1b, splitbuf mid)
    b.vT      = (unsigned short*)alloc(BDS * 2);         // 8 MB (splitbuf hi, image)
    b.P       = (unsigned short*)alloc(SS * 2);          // 4 MB
    b.h       = (unsigned short*)alloc(MD * 4 * 2);      // 32 MB (also scores)
    b.WqkvT   = (unsigned short*)alloc(3LL * 1024 * 1024 * 2);  // 6 MB
    b.W1T     = (unsigned short*)alloc(4096LL * 1024 * 2);      // 8 MB
    b.W2T     = (unsigned short*)alloc(4096LL * 1024 * 2);      // 8 MB
    b.f32buf  = (float*)alloc(MD * 4);                   // 16 MB
    b.bqkv    = (float*)alloc(3LL * 1024 * 4);
    b.ktot    = (float*)alloc(8192LL * 4);
    b.ktot_part = (float*)alloc(8192LL * KTOT_NCH * 4);
    b.part    = (double*)alloc(2048LL * 8);
    b.stats   = (float*)alloc(256);

    run_branch(text,  tw, true,  out_text, 8, 512, 1024, b, stream);
    run_branch(image, iw, false, out_img,  8, 196, 768,  b, stream);
}

// Round 18
// 436.789 us; speedup vs baseline: 1.1684x; 1.0037x over previous
//
#include <hip/hip_runtime.h>
#include <math.h>

typedef float  f32x4  __attribute__((ext_vector_type(4)));
typedef short  bf16x8 __attribute__((ext_vector_type(8)));

__device__ __forceinline__ unsigned short f2bf(float f) {
    union { float f; unsigned u; } v; v.f = f;
    unsigned u = v.u;
    return (unsigned short)((u + 0x7FFFu + ((u >> 16) & 1u)) >> 16);
}
__device__ __forceinline__ float bf2f(unsigned short u) {
    union { unsigned u; float f; } v; v.u = (unsigned)u << 16; return v.f;
}

#define GLOAD_LDS16(g, l)                                                      \
    __builtin_amdgcn_global_load_lds(                                          \
        (const __attribute__((address_space(1))) void*)(g),                    \
        (__attribute__((address_space(3))) void*)(l), 16, 0, 0)

// ---------------------------------------------------------------------------
// gemm4 (r12-verified best): 128x128 tile (MR=4,NR=2), BK=64, 8 waves,
// 2 LDS dbuf (64 KB -> 2 blocks/CU), stage-first + one barrier/K-tile,
// both-sides XOR swizzle (0 bank conflicts, verified r11/r12), setprio.
// A: bf16 [M,K] lda; BT: bf16 [N,K] ldb; C: fp32 or bf16, ldc.
// Batched via blockIdx.z. K%64==0. A-staging may over-read rows past M
// (workspace buffers have slack); C-writes are guarded.
// ---------------------------------------------------------------------------
template<int MR, int NR, bool OUT_BF16, bool RELU>
__global__ __launch_bounds__(512, 4)
void gemm4_bf16(const unsigned short* __restrict__ A,
                const unsigned short* __restrict__ BT,
                const float* __restrict__ bias, void* __restrict__ Cv,
                int M, int N, int K, int lda, int ldb, int ldc,
                long long sA, long long sB, long long sC, float alpha,
                int gx, int gy)
{
    constexpr int BK = 64;
    constexpr int WM = MR * 16, WN = NR * 16;
    constexpr int BM = 2 * WM, BN = 4 * WN;
    __shared__ unsigned short Asm[2][BM * BK];
    __shared__ unsigned short Bsm[2][BN * BK];

    A  += (long long)blockIdx.z * sA;
    BT += (long long)blockIdx.z * sB;
    char* Cb = (char*)Cv + (long long)blockIdx.z * sC * (OUT_BF16 ? 2 : 4);

    // bijective XCD swizzle (m204); n-fastest within each XCD chunk
    const int nwg = gx * gy;
    int orig = blockIdx.x;
    int xcd = orig & 7, sidx = orig >> 3;
    int qq = nwg >> 3, rr = nwg & 7;
    int wg = (xcd < rr ? xcd * (qq + 1) : rr * (qq + 1) + (xcd - rr) * qq) + sidx;
    const int row0 = (wg / gx) * BM;
    const int col0 = (wg % gx) * BN;

    const int tid  = threadIdx.x;
    const int lane = tid & 63;
    const int wave = tid >> 6;
    const int wr   = wave >> 2;
    const int wc   = wave & 3;

    const int lrow = lane & 15;
    const int cgrp = lane >> 4;

    f32x4 acc[MR][NR] = {};

    // staging: 512 thr x 16B = 8 KB = 64 rows x 128 B per issue; linear LDS
    // dest, source chunk pre-swizzled: LDS physical chunk p at row r holds
    // logical chunk p^(r&7).   [both-sides swizzle, verified r11/r12]
    const int srl = tid >> 3;
    const int scl = (tid & 7) ^ (srl & 7);

    auto stage = [&](int buf, int k0) {
        #pragma unroll
        for (int is = 0; is < BM / 64; ++is)
            GLOAD_LDS16(A + (long long)(row0 + is * 64 + srl) * lda + (k0 + scl * 8),
                        &Asm[buf][is * 64 * BK + tid * 8]);
        #pragma unroll
        for (int is = 0; is < BN / 64; ++is)
            GLOAD_LDS16(BT + (long long)(col0 + is * 64 + srl) * ldb + (k0 + scl * 8),
                        &Bsm[buf][is * 64 * BK + tid * 8]);
    };

    const int nt = K / BK;
    stage(0, 0);
    __syncthreads();

    for (int t = 0; t < nt; ++t) {
        if (t + 1 < nt) stage((t + 1) & 1, (t + 1) * BK);
        const int cur = t & 1;

        bf16x8 a_[2][MR], b_[2][NR];
        #pragma unroll
        for (int kk = 0; kk < 2; ++kk) {
            #pragma unroll
            for (int mf = 0; mf < MR; ++mf) {
                int row = wr * WM + mf * 16 + lrow;
                int phys = (kk * 4 + cgrp) ^ (row & 7);
                a_[kk][mf] = *(const bf16x8*)&Asm[cur][row * BK + phys * 8];
            }
            #pragma unroll
            for (int nf = 0; nf < NR; ++nf) {
                int row = wc * WN + nf * 16 + lrow;
                int phys = (kk * 4 + cgrp) ^ (row & 7);
                b_[kk][nf] = *(const bf16x8*)&Bsm[cur][row * BK + phys * 8];
            }
        }

        __builtin_amdgcn_s_setprio(1);
        #pragma unroll
        for (int kk = 0; kk < 2; ++kk)
            #pragma unroll
            for (int mf = 0; mf < MR; ++mf)
                #pragma unroll
                for (int nf = 0; nf < NR; ++nf)
                    acc[mf][nf] = __builtin_amdgcn_mfma_f32_16x16x32_bf16(
                        a_[kk][mf], b_[kk][nf], acc[mf][nf], 0, 0, 0);
        __builtin_amdgcn_s_setprio(0);

        __syncthreads();
    }

    // C/D layout: col = lane&15, row = (lane>>4)*4 + j   [m89 verified]
    const int crow = cgrp * 4;
    const int ccol = lane & 15;
    #pragma unroll
    for (int mf = 0; mf < MR; ++mf) {
        int rbase = row0 + wr * WM + mf * 16 + crow;
        #pragma unroll
        for (int nf = 0; nf < NR; ++nf) {
            int c = col0 + wc * WN + nf * 16 + ccol;
            if (c >= N) continue;
            float bv = bias ? bias[c] : 0.f;
            #pragma unroll
            for (int j = 0; j < 4; ++j) {
                int r = rbase + j;
                if (r >= M) continue;
                float v = acc[mf][nf][j] * alpha + bv;
                if (RELU) v = fmaxf(v, 0.f);
                if (OUT_BF16)
                    ((unsigned short*)Cb)[(long long)r * ldc + c] = f2bf(v);
                else
                    ((float*)Cb)[(long long)r * ldc + c] = v;
            }
        }
    }
}

template<int MR, int NR>
static void gemm4_t(bool outBf16, bool relu,
                    const unsigned short* A, const unsigned short* BT, const float* bias,
                    void* C, int M, int N, int K, int lda, int ldb, int ldc,
                    int batch, long long sA, long long sB, long long sC,
                    float alpha, hipStream_t st)
{
    const int BM = 2 * MR * 16, BN = 4 * NR * 16;
    int gx = (N + BN - 1) / BN, gy = (M + BM - 1) / BM;
    dim3 grid(gx * gy, 1, batch);
    if (outBf16) {
        if (relu) gemm4_bf16<MR, NR, true , true ><<<grid, 512, 0, st>>>(A, BT, bias, C, M, N, K, lda, ldb, ldc, sA, sB, sC, alpha, gx, gy);
        else      gemm4_bf16<MR, NR, true , false><<<grid, 512, 0, st>>>(A, BT, bias, C, M, N, K, lda, ldb, ldc, sA, sB, sC, alpha, gx, gy);
    } else {
        if (relu) gemm4_bf16<MR, NR, false, true ><<<grid, 512, 0, st>>>(A, BT, bias, C, M, N, K, lda, ldb, ldc, sA, sB, sC, alpha, gx, gy);
        else      gemm4_bf16<MR, NR, false, false><<<grid, 512, 0, st>>>(A, BT, bias, C, M, N, K, lda, ldb, ldc, sA, sB, sC, alpha, gx, gy);
    }
}

// ---------------------------------------------------------------------------
// old m97-structure engine, kept for the small batched GEMMs (scores, PV)
// ---------------------------------------------------------------------------
template<int BM, int BN, bool OUT_BF16>
__global__ __launch_bounds__(256)
void gemm_bf16(const unsigned short* __restrict__ A,
               const unsigned short* __restrict__ BT,
               const float* __restrict__ bias, void* __restrict__ Cv,
               int M, int N, int K, int lda, int ldb, int ldc,
               long long sA, long long sB, long long sC, float alpha,
               int gx, int gy)
{
    constexpr int BK = 32;
    constexpr int WM = BM / 2, WN = BN / 2;
    constexpr int MR = WM / 16, NR = WN / 16;
    __shared__ unsigned short Asm[BM * BK];
    __shared__ unsigned short Bsm[BN * BK];

    A  += (long long)blockIdx.z * sA;
    BT += (long long)blockIdx.z * sB;
    char* Cb = (char*)Cv + (long long)blockIdx.z * sC * (OUT_BF16 ? 2 : 4);

    const int nwg = gx * gy;
    int orig = blockIdx.x;
    int xcd = orig & 7, sidx = orig >> 3;
    int qq = nwg >> 3, rr = nwg & 7;
    int wg = (xcd < rr ? xcd * (qq + 1) : rr * (qq + 1) + (xcd - rr) * qq) + sidx;
    const int row0 = (wg % gy) * BM;
    const int col0 = (wg / gy) * BN;

    const int tid  = threadIdx.x;
    const int lane = tid & 63;
    const int wave = tid >> 6;
    const int wr   = wave >> 1;
    const int wc   = wave & 1;

    const int srow = tid >> 2;
    const int skel = (tid & 3) * 8;

    f32x4 acc[MR][NR] = {};

    const int lrow = lane & 15;
    const int lk   = (lane >> 4) * 8;

    for (int k0 = 0; k0 < K; k0 += BK) {
        #pragma unroll
        for (int is = 0; is < BM / 64; ++is)
            GLOAD_LDS16(A + (long long)(row0 + is * 64 + srow) * lda + (k0 + skel),
                        &Asm[(is * 64 + srow) * BK + skel]);
        #pragma unroll
        for (int is = 0; is < BN / 64; ++is)
            GLOAD_LDS16(BT + (long long)(col0 + is * 64 + srow) * ldb + (k0 + skel),
                        &Bsm[(is * 64 + srow) * BK + skel]);
        __syncthreads();

        bf16x8 af[MR], bfr[NR];
        #pragma unroll
        for (int mf = 0; mf < MR; ++mf)
            af[mf] = *(const bf16x8*)&Asm[(wr * WM + mf * 16 + lrow) * BK + lk];
        #pragma unroll
        for (int nf = 0; nf < NR; ++nf)
            bfr[nf] = *(const bf16x8*)&Bsm[(wc * WN + nf * 16 + lrow) * BK + lk];
        #pragma unroll
        for (int mf = 0; mf < MR; ++mf)
            #pragma unroll
            for (int nf = 0; nf < NR; ++nf)
                acc[mf][nf] = __builtin_amdgcn_mfma_f32_16x16x32_bf16(
                    af[mf], bfr[nf], acc[mf][nf], 0, 0, 0);
        __syncthreads();
    }

    const int crow = (lane >> 4) * 4;
    const int ccol = lane & 15;
    #pragma unroll
    for (int mf = 0; mf < MR; ++mf) {
        int rbase = row0 + wr * WM + mf * 16 + crow;
        #pragma unroll
        for (int nf = 0; nf < NR; ++nf) {
            int c = col0 + wc * WN + nf * 16 + ccol;
            if (c >= N) continue;
            float bv = bias ? bias[c] : 0.f;
            #pragma unroll
            for (int j = 0; j < 4; ++j) {
                int r = rbase + j;
                if (r >= M) continue;
                float v = acc[mf][nf][j] * alpha + bv;
                if (OUT_BF16)
                    ((unsigned short*)Cb)[(long long)r * ldc + c] = f2bf(v);
                else
                    ((float*)Cb)[(long long)r * ldc + c] = v;
            }
        }
    }
}

template<int BM, int BN>
static void gemm_t(bool outBf16,
                   const unsigned short* A, const unsigned short* BT, const float* bias,
                   void* C, int M, int N, int K, int lda, int ldb, int ldc,
                   int batch, long long sA, long long sB, long long sC,
                   float alpha, hipStream_t st)
{
    int gx = (N + BN - 1) / BN, gy = (M + BM - 1) / BM;
    dim3 grid(gx * gy, 1, batch);
    if (outBf16)
        gemm_bf16<BM, BN, true ><<<grid, 256, 0, st>>>(A, BT, bias, C, M, N, K, lda, ldb, ldc, sA, sB, sC, alpha, gx, gy);
    else
        gemm_bf16<BM, BN, false><<<grid, 256, 0, st>>>(A, BT, bias, C, M, N, K, lda, ldb, ldc, sA, sB, sC, alpha, gx, gy);
}

// ---------------------------------------------------------------------------
// split-K reduce + bias + residual(x) + whole-norm stats (r12-proven,
// two-kernel chain: NO inter-block communication, deterministic)
// ---------------------------------------------------------------------------
__global__ void splitk_stats_kernel(const float4* __restrict__ part,
                                    const float4* __restrict__ bias,
                                    const float4* __restrict__ x,
                                    float4* __restrict__ z,
                                    double* __restrict__ dpart,
                                    long long n4, int N4, int nsplit, long long stride4)
{
    __shared__ double rs[256], rs2[256];
    int tid = threadIdx.x;
    long long i = (long long)blockIdx.x * blockDim.x + tid;
    long long gs = (long long)gridDim.x * blockDim.x;
    double s = 0.0, s2 = 0.0;
    for (; i < n4; i += gs) {
        float4 a = part[i];
        for (int sp = 1; sp < nsplit; ++sp) {
            float4 b = part[(long long)sp * stride4 + i];
            a.x += b.x; a.y += b.y; a.z += b.z; a.w += b.w;
        }
        float4 bv = bias[(int)(i % N4)];
        float4 xv = x[i];
        a.x += bv.x + xv.x; a.y += bv.y + xv.y; a.z += bv.z + xv.z; a.w += bv.w + xv.w;
        z[i] = a;
        s  += (double)a.x + (double)a.y + (double)a.z + (double)a.w;
        s2 += (double)a.x * a.x + (double)a.y * a.y + (double)a.z * a.z + (double)a.w * a.w;
    }
    rs[tid] = s; rs2[tid] = s2; __syncthreads();
    for (int k = 128; k > 0; k >>= 1) {
        if (tid < k) { rs[tid] += rs[tid + k]; rs2[tid] += rs2[tid + k]; }
        __syncthreads();
    }
    if (tid == 0) { dpart[2 * blockIdx.x] = rs[0]; dpart[2 * blockIdx.x + 1] = rs2[0]; }
}

__global__ void stats_kernel(const float4* __restrict__ a, const float4* __restrict__ f,
                             double* __restrict__ part, long long n4)
{
    __shared__ double rs[256], rs2[256];
    int tid = threadIdx.x;
    long long i = (long long)blockIdx.x * blockDim.x + tid;
    long long stride = (long long)gridDim.x * blockDim.x;
    double s = 0.0, s2 = 0.0;
    for (; i < n4; i += stride) {
        float4 av = a[i], fv = f[i];
        float z0 = av.x + fv.x, z1 = av.y + fv.y, z2 = av.z + fv.z, z3 = av.w + fv.w;
        s  += (double)z0 + (double)z1 + (double)z2 + (double)z3;
        s2 += (double)z0 * z0 + (double)z1 * z1 + (double)z2 * z2 + (double)z3 * z3;
    }
    rs[tid] = s; rs2[tid] = s2; __syncthreads();
    for (int k = 128; k > 0; k >>= 1) {
        if (tid < k) { rs[tid] += rs[tid + k]; rs2[tid] += rs2[tid + k]; }
        __syncthreads();
    }
    if (tid == 0) { part[2 * blockIdx.x] = rs[0]; part[2 * blockIdx.x + 1] = rs2[0]; }
}

__global__ void finish_stats(const double* __restrict__ part, int npart,
                             float* __restrict__ stats, double n)
{
    __shared__ double rs[256], rs2[256];
    int tid = threadIdx.x;
    double s = 0.0, s2 = 0.0;
    for (int i = tid; i < npart; i += 256) { s += part[2 * i]; s2 += part[2 * i + 1]; }
    rs[tid] = s; rs2[tid] = s2; __syncthreads();
    for (int k = 128; k > 0; k >>= 1) {
        if (tid < k) { rs[tid] += rs[tid + k]; rs2[tid] += rs2[tid + k]; }
        __syncthreads();
    }
    if (tid == 0) {
        double mu  = rs[0] / n;
        double var = rs2[0] / n - mu * mu;
        stats[0] = (float)mu;
        stats[1] = (float)(1.0 / sqrt(var + 1e-6));
    }
}

// norm apply recomputing z = a + f, bf16 out (norm1 -> y1)
__global__ void norm_apply_kernel(const float4* __restrict__ a, const float4* __restrict__ f,
                                  const float4* __restrict__ nw, const float4* __restrict__ nb,
                                  const float* __restrict__ stats, ushort4* __restrict__ out,
                                  long long n4)
{
    float mu = stats[0], rstd = stats[1];
    long long i = (long long)blockIdx.x * blockDim.x + threadIdx.x;
    long long stride = (long long)gridDim.x * blockDim.x;
    for (; i < n4; i += stride) {
        float4 av = a[i], fv = f[i], wv = nw[i], bv = nb[i];
        ushort4 o;
        o.x = f2bf((av.x + fv.x - mu) * rstd * wv.x + bv.x);
        o.y = f2bf((av.y + fv.y - mu) * rstd * wv.y + bv.y);
        o.z = f2bf((av.z + fv.z - mu) * rstd * wv.z + bv.z);
        o.w = f2bf((av.w + fv.w - mu) * rstd * wv.w + bv.w);
        out[i] = o;
    }
}

// norm apply reading z directly (z already includes residual), fp32 out
__global__ void norm_apply_z_kernel(const float4* __restrict__ z,
                                    const float4* __restrict__ nw, const float4* __restrict__ nb,
                                    const float* __restrict__ stats, float4* __restrict__ out,
                                    long long n4)
{
    float mu = stats[0], rstd = stats[1];
    long long i = (long long)blockIdx.x * blockDim.x + threadIdx.x;
    long long stride = (long long)gridDim.x * blockDim.x;
    for (; i < n4; i += stride) {
        float4 zv = z[i], wv = nw[i], bv = nb[i];
        float4 o;
        o.x = (zv.x - mu) * rstd * wv.x + bv.x;
        o.y = (zv.y - mu) * rstd * wv.y + bv.y;
        o.z = (zv.z - mu) * rstd * wv.z + bv.z;
        o.w = (zv.w - mu) * rstd * wv.w + bv.w;
        out[i] = o;
    }
}

// ---------------------------------------------------------------------------
// elementwise cast f32 -> bf16
// ---------------------------------------------------------------------------
__global__ void cast_bf16_kernel(const float4* __restrict__ in,
                                 ushort4* __restrict__ out, long long n4)
{
    long long i = (long long)blockIdx.x * blockDim.x + threadIdx.x;
    long long stride = (long long)gridDim.x * blockDim.x;
    for (; i < n4; i += stride) {
        float4 v = in[i];
        ushort4 o;
        o.x = f2bf(v.x); o.y = f2bf(v.y); o.z = f2bf(v.z); o.w = f2bf(v.w);
        out[i] = o;
    }
}

// concat bias: out = [bq | bk | bv]  (pure data-parallel, no cross-block dep)
__global__ void concat_bias_kernel(const float* __restrict__ bq, const float* __restrict__ bk,
                                   const float* __restrict__ bv, float* __restrict__ out, int D)
{
    int i = blockIdx.x * 256 + threadIdx.x;
    if (i < D) { out[i] = bq[i]; out[D + i] = bk[i]; out[2 * D + i] = bv[i]; }
}

// ---------------------------------------------------------------------------
// transpose + cast: src f32 [R,C] -> dst bf16 [C, Rpad]
// ---------------------------------------------------------------------------
__global__ void transpose_cast_kernel(const float* __restrict__ src,
                                      unsigned short* __restrict__ dst,
                                      int R, int C, int Rpad,
                                      long long sSrc, long long sDst)
{
    __shared__ float t[32][33];
    src += (long long)blockIdx.z * sSrc;
    dst += (long long)blockIdx.z * sDst;
    int r0 = blockIdx.x * 32, c0 = blockIdx.y * 32;
    int tx = threadIdx.x & 31, ty = threadIdx.x >> 5;
    #pragma unroll
    for (int i = 0; i < 32; i += 8) {
        int r = r0 + ty + i, c = c0 + tx;
        t[ty + i][tx] = (r < R && c < C) ? src[(long long)r * C + c] : 0.f;
    }
    __syncthreads();
    #pragma unroll
    for (int i = 0; i < 32; i += 8) {
        int c = c0 + ty + i, r = r0 + tx;
        if (c < C && r < Rpad)
            dst[(long long)c * Rpad + r] = f2bf(t[tx][ty + i]);
    }
}

// three same-shape square transposes in one launch (QKV weights), z selects
__global__ void transpose_cast3_kernel(const float* __restrict__ s0,
                                       const float* __restrict__ s1,
                                       const float* __restrict__ s2,
                                       unsigned short* __restrict__ dst, int D)
{
    __shared__ float t[32][33];
    const float* src = blockIdx.z == 0 ? s0 : (blockIdx.z == 1 ? s1 : s2);
    dst += (long long)blockIdx.z * D * D;
    int r0 = blockIdx.x * 32, c0 = blockIdx.y * 32;
    int tx = threadIdx.x & 31, ty = threadIdx.x >> 5;
    #pragma unroll
    for (int i = 0; i < 32; i += 8)
        t[ty + i][tx] = src[(long long)(r0 + ty + i) * D + (c0 + tx)];
    __syncthreads();
    #pragma unroll
    for (int i = 0; i < 32; i += 8)
        dst[(long long)(c0 + ty + i) * D + (r0 + tx)] = f2bf(t[tx][ty + i]);
}

// transpose bf16 [R,C] (row stride ldS) -> bf16 [C, Rpad]
__global__ void transpose_bf16_kernel(const unsigned short* __restrict__ src,
                                      unsigned short* __restrict__ dst,
                                      int R, int C, int Rpad, int ldS,
                                      long long sSrc, long long sDst)
{
    __shared__ unsigned short t[32][33];
    src += (long long)blockIdx.z * sSrc;
    dst += (long long)blockIdx.z * sDst;
    int r0 = blockIdx.x * 32, c0 = blockIdx.y * 32;
    int tx = threadIdx.x & 31, ty = threadIdx.x >> 5;
    #pragma unroll
    for (int i = 0; i < 32; i += 8) {
        int r = r0 + ty + i, c = c0 + tx;
        t[ty + i][tx] = (r < R && c < C) ? src[(long long)r * ldS + c] : (unsigned short)0;
    }
    __syncthreads();
    #pragma unroll
    for (int i = 0; i < 32; i += 8) {
        int c = c0 + ty + i, r = r0 + tx;
        if (c < C && r < Rpad)
            dst[(long long)c * Rpad + r] = t[tx][ty + i];
    }
}

// ---------------------------------------------------------------------------
// Ktot two-stage deterministic reduction over s (bf16 input, strided ld)
// ---------------------------------------------------------------------------
#define KTOT_NCH 16
__global__ void ktot_partial_bf16(const unsigned short* __restrict__ k,
                                  float* __restrict__ part,
                                  int B, int S, int D, int ld)
{
    int bch = blockIdx.x;
    int b  = bch / KTOT_NCH;
    int ch = bch % KTOT_NCH;
    int d  = blockIdx.y * 256 + threadIdx.x;
    if (d >= D) return;
    int len = (S + KTOT_NCH - 1) / KTOT_NCH;
    int lo = ch * len;
    int hi = lo + len < S ? lo + len : S;
    const unsigned short* kp = k + ((long long)b * S + lo) * ld + d;
    float s = 0.f;
    for (int t = lo; t < hi; ++t, kp += ld) s += bf2f(*kp);
    part[(long long)bch * D + d] = s;
}

__global__ void ktot_finish_kernel(const float* __restrict__ part,
                                   float* __restrict__ ktot, int B, int D)
{
    int idx = blockIdx.x * blockDim.x + threadIdx.x;
    if (idx >= B * D) return;
    int b = idx / D, d = idx % D;
    float s = 0.f;
    #pragma unroll
    for (int ch = 0; ch < KTOT_NCH; ++ch)
        s += part[((long long)b * KTOT_NCH + ch) * D + d];
    ktot[idx] = s;
}

// ---------------------------------------------------------------------------
// kk[b,s,d] = (Ktot[b,d] + (e-1)*window_sum) / Z_s  from bf16 k (stride ld)
// ---------------------------------------------------------------------------
__global__ void kk_bf16_kernel(const unsigned short* __restrict__ k,
                               const float* __restrict__ ktot,
                               unsigned short* __restrict__ kk,
                               int B, int S, int D, int ld)
{
    long long idx = (long long)blockIdx.x * blockDim.x + threadIdx.x;
    int D4 = D >> 2;
    long long n4 = (long long)B * S * D4;
    if (idx >= n4) return;
    int d4 = (int)(idx % D4);
    long long bs = idx / D4;
    int s = (int)(bs % S);
    int b = (int)(bs / S);
    int lo = s - 2 > 0 ? s - 2 : 0;
    int hi = s + 2 < S - 1 ? s + 2 : S - 1;
    int c = hi - lo + 1;
    const float E = 2.718281828459045f;
    float Zinv = 1.f / ((float)(S - c) + E * (float)c);

    float w0 = 0.f, w1 = 0.f, w2 = 0.f, w3 = 0.f;
    const unsigned short* kp = k + ((long long)b * S + lo) * ld + d4 * 4;
    for (int t = lo; t <= hi; ++t, kp += ld) {
        ushort4 kv = *(const ushort4*)kp;
        w0 += bf2f(kv.x); w1 += bf2f(kv.y); w2 += bf2f(kv.z); w3 += bf2f(kv.w);
    }
    float4 tot = *((const float4*)(ktot + b * D) + d4);
    ushort4 o;
    o.x = f2bf((tot.x + (E - 1.f) * w0) * Zinv);
    o.y = f2bf((tot.y + (E - 1.f) * w1) * Zinv);
    o.z = f2bf((tot.z + (E - 1.f) * w2) * Zinv);
    o.w = f2bf((tot.w + (E - 1.f) * w3) * Zinv);
    ((ushort4*)(kk + ((long long)b * S + s) * D))[d4] = o;
}

// ---------------------------------------------------------------------------
// row softmax: fp32 scores [rows][Spad] -> bf16 P, pads = 0
// ---------------------------------------------------------------------------
__global__ void softmax_rows_bf16(const float* __restrict__ sc,
                                  unsigned short* __restrict__ P, int S, int Spad)
{
    long long row = blockIdx.x;
    const float* p = sc + row * (long long)Spad;
    unsigned short* o = P + row * (long long)Spad;
    int tid = threadIdx.x;
    __shared__ float red[256];

    float m = -INFINITY;
    for (int t = tid; t < S; t += 256) m = fmaxf(m, p[t]);
    red[tid] = m; __syncthreads();
    for (int s = 128; s > 0; s >>= 1) {
        if (tid < s) red[tid] = fmaxf(red[tid], red[tid + s]);
        __syncthreads();
    }
    m = red[0];
    __syncthreads();

    float sum = 0.f;
    for (int t = tid; t < S; t += 256) sum += __expf(p[t] - m);
    red[tid] = sum; __syncthreads();
    for (int s = 128; s > 0; s >>= 1) {
        if (tid < s) red[tid] += red[tid + s];
        __syncthreads();
    }
    float inv = 1.f / red[0];
    for (int t = tid; t < Spad; t += 256)
        o[t] = (t < S) ? f2bf(__expf(p[t] - m) * inv) : (unsigned short)0;
}

// ---------------------------------------------------------------------------
// host-side orchestration
// ---------------------------------------------------------------------------
struct Bufs {
    unsigned short *xb, *qkv, *kkb, *vT, *P, *h, *WqkvT, *W1T, *W2T;
    float *f32buf, *bqkv, *ktot, *ktot_part, *stats;
    double *part;
};

static void run_branch(const float* x, const float* const* w, bool big,
                       float* out, int B, int S, int D, const Bufs& wsb, hipStream_t st)
{
    const float *Wq = w[0], *bq = w[1], *Wk = w[2], *bk = w[3], *Wv = w[4], *bv = w[5];
    const float *W1 = w[6], *b1 = w[7], *W2 = w[8], *b2 = w[9], *nw = w[10], *nb = w[11];

    const int Spad = (S + 31) & ~31;
    const long long M = (long long)B * S;
    const long long n = M * D;
    const long long n4 = n / 4;
    const float inv_sqrt_d = (float)(1.0 / sqrt((double)D));
    const int D3 = 3 * D, D4 = 4 * D;

    unsigned short* y1b = wsb.kkb;           // alias: kkb dead after scores GEMM
    float* scores = (float*)wsb.h;           // alias: h free until FFN1
    float* splitbuf = (float*)wsb.qkv;       // alias: qkv+kkb+vT dead during FFN2

    // casts: x -> xb ; weights -> transposed bf16 (QKV concat), bias concat
    cast_bf16_kernel<<<1024, 256, 0, st>>>((const float4*)x, (ushort4*)wsb.xb, n4);
    transpose_cast3_kernel<<<dim3(D / 32, D / 32, 3), 256, 0, st>>>(Wq, Wk, Wv, wsb.WqkvT, D);
    transpose_cast_kernel<<<dim3((D + 31) / 32, (D4 + 31) / 32, 1), 256, 0, st>>>(W1, wsb.W1T, D, D4, D, 0, 0);
    transpose_cast_kernel<<<dim3((D4 + 31) / 32, (D + 31) / 32, 1), 256, 0, st>>>(W2, wsb.W2T, D4, D, D4, 0, 0);
    concat_bias_kernel<<<(D + 255) / 256, 256, 0, st>>>(bq, bk, bv, wsb.bqkv, D);

    // fused QKV: [M,3D] bf16 (gemm4 128x128)
    gemm4_t<4, 2>(true, false, wsb.xb, wsb.WqkvT, wsb.bqkv, wsb.qkv,
                  (int)M, D3, D, D, D, D3, 1, 0, 0, 0, 1.f, st);

    // kk = softmax(band mask) @ k  (analytic, bf16 k at column offset D)
    const unsigned short* kcol = wsb.qkv + D;
    ktot_partial_bf16<<<dim3(B * KTOT_NCH, (D + 255) / 256), 256, 0, st>>>(kcol, wsb.ktot_part, B, S, D, D3);
    ktot_finish_kernel<<<(B * D + 255) / 256, 256, 0, st>>>(wsb.ktot_part, wsb.ktot, B, D);
    kk_bf16_kernel<<<(int)((n4 + 255) / 256), 256, 0, st>>>(kcol, wsb.ktot, wsb.kkb, B, S, D, D3);

    // vT bf16 [B][D][Spad]  (v at column offset 2D)
    transpose_bf16_kernel<<<dim3((Spad + 31) / 32, (D + 31) / 32, B), 256, 0, st>>>(
        wsb.qkv + 2 * D, wsb.vT, S, D, Spad, D3, (long long)S * D3, (long long)D * Spad);

    // scores = q @ kk^T / sqrt(D)
    gemm_t<64, 64>(false, wsb.qkv, wsb.kkb, nullptr, scores, S, S, D, D3, D, Spad,
                   B, (long long)S * D3, (long long)S * D, (long long)S * Spad, inv_sqrt_d, st);
    softmax_rows_bf16<<<(int)M, 256, 0, st>>>(scores, wsb.P, S, Spad);

    // attn = P @ v -> f32buf
    gemm_t<128, 64>(false, wsb.P, wsb.vT, nullptr, wsb.f32buf, S, D, Spad, Spad, Spad, D,
                    B, (long long)S * Spad, (long long)D * Spad, (long long)S * D, 1.f, st);

    // norm1: y1 = whole_norm(attn + x) -> bf16 (into kkb region)
    stats_kernel<<<1024, 256, 0, st>>>((const float4*)wsb.f32buf, (const float4*)x, wsb.part, n4);
    finish_stats<<<1, 256, 0, st>>>(wsb.part, 1024, wsb.stats, (double)n);
    norm_apply_kernel<<<2048, 256, 0, st>>>((const float4*)wsb.f32buf, (const float4*)x,
        (const float4*)nw, (const float4*)nb, wsb.stats, (ushort4*)y1b, n4);

    // FFN1 -> h (bf16, relu), gemm4 128x128
    gemm4_t<4, 2>(true, true, y1b, wsb.W1T, b1, wsb.h, (int)M, D4, D, D, D, D4, 1, 0, 0, 0, 1.f, st);

    // FFN2 split-K -> partials (fp32), reduce+bias+residual+stats, finish, apply
    {
        int nsplit = big ? 2 : 8;
        int Ksp = D4 / nsplit;
        gemm4_t<4, 2>(false, false, wsb.h, wsb.W2T, nullptr, splitbuf,
                      (int)M, D, Ksp, D4, D4, D,
                      nsplit, Ksp, Ksp, M * D, 1.f, st);
        splitk_stats_kernel<<<1024, 256, 0, st>>>((const float4*)splitbuf, (const float4*)b2,
                                                  (const float4*)x, (float4*)wsb.f32buf,
                                                  wsb.part, n4, D / 4, nsplit, n4);
        finish_stats<<<1, 256, 0, st>>>(wsb.part, 1024, wsb.stats, (double)n);
        norm_apply_z_kernel<<<2048, 256, 0, st>>>((const float4*)wsb.f32buf,
            (const float4*)nw, (const float4*)nb, wsb.stats, (float4*)out, n4);
    }
}

extern "C" void kernel_launch(void* const* d_in, const int* in_sizes, int n_in,
                              void* d_out, int out_size, void* d_ws, size_t ws_size,
                              hipStream_t stream)
{
    const float* text  = (const float*)d_in[0];
    const float* image = (const float*)d_in[1];
    const float* tw[12];
    const float* iw[12];
    for (int i = 0; i < 12; ++i) tw[i] = (const float*)d_in[2 + i];
    for (int i = 0; i < 12; ++i) iw[i] = (const float*)d_in[14 + i];

    float* out_text = (float*)d_out;                 // [8,512,1024]
    float* out_img  = out_text + 8LL * 512 * 1024;   // [8,196,768]

    // workspace layout (text-branch sizes; image reuses)
    char* p = (char*)d_ws;
    auto alloc = [&](long long bytes) {
        char* r = p;
        p += (bytes + 255) & ~255LL;
        return r;
    };
    const long long MD  = 4096LL * 1024;    // B*S*D
    const long long BDS = 8LL * 1024 * 512; // B*D*Spad
    const long long SS  = 8LL * 512 * 512;  // B*S*Spad
    Bufs b;
    b.xb      = (unsigned short*)alloc(MD * 2);          // 8 MB
    b.qkv     = (unsigned short*)alloc(MD * 3 * 2);      // 24 MB (splitbuf lo)
    b.kkb     = (unsigned short*)alloc(MD * 2);          // 8 MB (y1b, splitbuf mid)
    b.vT      = (unsigned short*)alloc(BDS * 2);         // 8 MB (splitbuf hi, image)
    b.P       = (unsigned short*)alloc(SS * 2);          // 4 MB
    b.h       = (unsigned short*)alloc(MD * 4 * 2);      // 32 MB (also scores)
    b.WqkvT   = (unsigned short*)alloc(3LL * 1024 * 1024 * 2);  // 6 MB
    b.W1T     = (unsigned short*)alloc(4096LL * 1024 * 2);      // 8 MB
    b.W2T     = (unsigned short*)alloc(4096LL * 1024 * 2);      // 8 MB
    b.f32buf  = (float*)alloc(MD * 4);                   // 16 MB
    b.bqkv    = (float*)alloc(3LL * 1024 * 4);
    b.ktot    = (float*)alloc(8192LL * 4);
    b.ktot_part = (float*)alloc(8192LL * KTOT_NCH * 4);
    b.part    = (double*)alloc(2048LL * 8);
    b.stats   = (float*)alloc(256);

    run_branch(text,  tw, true,  out_text, 8, 512, 1024, b, stream);
    run_branch(image, iw, false, out_img,  8, 196, 768,  b, stream);
}

// Round 19
// 431.043 us; speedup vs baseline: 1.1840x; 1.0133x over previous
//
#include <hip/hip_runtime.h>
#include <math.h>

typedef float  f32x4  __attribute__((ext_vector_type(4)));
typedef short  bf16x8 __attribute__((ext_vector_type(8)));

__device__ __forceinline__ unsigned short f2bf(float f) {
    union { float f; unsigned u; } v; v.f = f;
    unsigned u = v.u;
    return (unsigned short)((u + 0x7FFFu + ((u >> 16) & 1u)) >> 16);
}
__device__ __forceinline__ float bf2f(unsigned short u) {
    union { unsigned u; float f; } v; v.u = (unsigned)u << 16; return v.f;
}

#define GLOAD_LDS16(g, l)                                                      \
    __builtin_amdgcn_global_load_lds(                                          \
        (const __attribute__((address_space(1))) void*)(g),                    \
        (__attribute__((address_space(3))) void*)(l), 16, 0, 0)

// ---------------------------------------------------------------------------
// gemm4 (r12/r18-verified best): 128x128 tile (MR=4,NR=2), BK=64, 8 waves,
// 2 LDS dbuf (64 KB -> 2 blocks/CU), stage-first + one barrier/K-tile,
// both-sides XOR swizzle (0 bank conflicts, verified r11/r12), setprio.
// A: bf16 [M,K] lda; BT: bf16 [N,K] ldb; C: fp32 or bf16, ldc.
// Batched via blockIdx.z. K%64==0. A-staging may over-read rows past M
// (workspace buffers have slack); C-writes are guarded.
// ---------------------------------------------------------------------------
template<int MR, int NR, bool OUT_BF16, bool RELU>
__global__ __launch_bounds__(512, 4)
void gemm4_bf16(const unsigned short* __restrict__ A,
                const unsigned short* __restrict__ BT,
                const float* __restrict__ bias, void* __restrict__ Cv,
                int M, int N, int K, int lda, int ldb, int ldc,
                long long sA, long long sB, long long sC, float alpha,
                int gx, int gy)
{
    constexpr int BK = 64;
    constexpr int WM = MR * 16, WN = NR * 16;
    constexpr int BM = 2 * WM, BN = 4 * WN;
    __shared__ unsigned short Asm[2][BM * BK];
    __shared__ unsigned short Bsm[2][BN * BK];

    A  += (long long)blockIdx.z * sA;
    BT += (long long)blockIdx.z * sB;
    char* Cb = (char*)Cv + (long long)blockIdx.z * sC * (OUT_BF16 ? 2 : 4);

    // bijective XCD swizzle (m204); n-fastest within each XCD chunk
    const int nwg = gx * gy;
    int orig = blockIdx.x;
    int xcd = orig & 7, sidx = orig >> 3;
    int qq = nwg >> 3, rr = nwg & 7;
    int wg = (xcd < rr ? xcd * (qq + 1) : rr * (qq + 1) + (xcd - rr) * qq) + sidx;
    const int row0 = (wg / gx) * BM;
    const int col0 = (wg % gx) * BN;

    const int tid  = threadIdx.x;
    const int lane = tid & 63;
    const int wave = tid >> 6;
    const int wr   = wave >> 2;
    const int wc   = wave & 3;

    const int lrow = lane & 15;
    const int cgrp = lane >> 4;

    f32x4 acc[MR][NR] = {};

    // staging: 512 thr x 16B = 8 KB = 64 rows x 128 B per issue; linear LDS
    // dest, source chunk pre-swizzled: LDS physical chunk p at row r holds
    // logical chunk p^(r&7).   [both-sides swizzle, verified r11/r12]
    const int srl = tid >> 3;
    const int scl = (tid & 7) ^ (srl & 7);

    auto stage = [&](int buf, int k0) {
        #pragma unroll
        for (int is = 0; is < BM / 64; ++is)
            GLOAD_LDS16(A + (long long)(row0 + is * 64 + srl) * lda + (k0 + scl * 8),
                        &Asm[buf][is * 64 * BK + tid * 8]);
        #pragma unroll
        for (int is = 0; is < BN / 64; ++is)
            GLOAD_LDS16(BT + (long long)(col0 + is * 64 + srl) * ldb + (k0 + scl * 8),
                        &Bsm[buf][is * 64 * BK + tid * 8]);
    };

    const int nt = K / BK;
    stage(0, 0);
    __syncthreads();

    for (int t = 0; t < nt; ++t) {
        if (t + 1 < nt) stage((t + 1) & 1, (t + 1) * BK);
        const int cur = t & 1;

        bf16x8 a_[2][MR], b_[2][NR];
        #pragma unroll
        for (int kk = 0; kk < 2; ++kk) {
            #pragma unroll
            for (int mf = 0; mf < MR; ++mf) {
                int row = wr * WM + mf * 16 + lrow;
                int phys = (kk * 4 + cgrp) ^ (row & 7);
                a_[kk][mf] = *(const bf16x8*)&Asm[cur][row * BK + phys * 8];
            }
            #pragma unroll
            for (int nf = 0; nf < NR; ++nf) {
                int row = wc * WN + nf * 16 + lrow;
                int phys = (kk * 4 + cgrp) ^ (row & 7);
                b_[kk][nf] = *(const bf16x8*)&Bsm[cur][row * BK + phys * 8];
            }
        }

        __builtin_amdgcn_s_setprio(1);
        #pragma unroll
        for (int kk = 0; kk < 2; ++kk)
            #pragma unroll
            for (int mf = 0; mf < MR; ++mf)
                #pragma unroll
                for (int nf = 0; nf < NR; ++nf)
                    acc[mf][nf] = __builtin_amdgcn_mfma_f32_16x16x32_bf16(
                        a_[kk][mf], b_[kk][nf], acc[mf][nf], 0, 0, 0);
        __builtin_amdgcn_s_setprio(0);

        __syncthreads();
    }

    // C/D layout: col = lane&15, row = (lane>>4)*4 + j   [m89 verified]
    const int crow = cgrp * 4;
    const int ccol = lane & 15;
    #pragma unroll
    for (int mf = 0; mf < MR; ++mf) {
        int rbase = row0 + wr * WM + mf * 16 + crow;
        #pragma unroll
        for (int nf = 0; nf < NR; ++nf) {
            int c = col0 + wc * WN + nf * 16 + ccol;
            if (c >= N) continue;
            float bv = bias ? bias[c] : 0.f;
            #pragma unroll
            for (int j = 0; j < 4; ++j) {
                int r = rbase + j;
                if (r >= M) continue;
                float v = acc[mf][nf][j] * alpha + bv;
                if (RELU) v = fmaxf(v, 0.f);
                if (OUT_BF16)
                    ((unsigned short*)Cb)[(long long)r * ldc + c] = f2bf(v);
                else
                    ((float*)Cb)[(long long)r * ldc + c] = v;
            }
        }
    }
}

template<int MR, int NR>
static void gemm4_t(bool outBf16, bool relu,
                    const unsigned short* A, const unsigned short* BT, const float* bias,
                    void* C, int M, int N, int K, int lda, int ldb, int ldc,
                    int batch, long long sA, long long sB, long long sC,
                    float alpha, hipStream_t st)
{
    const int BM = 2 * MR * 16, BN = 4 * NR * 16;
    int gx = (N + BN - 1) / BN, gy = (M + BM - 1) / BM;
    dim3 grid(gx * gy, 1, batch);
    if (outBf16) {
        if (relu) gemm4_bf16<MR, NR, true , true ><<<grid, 512, 0, st>>>(A, BT, bias, C, M, N, K, lda, ldb, ldc, sA, sB, sC, alpha, gx, gy);
        else      gemm4_bf16<MR, NR, true , false><<<grid, 512, 0, st>>>(A, BT, bias, C, M, N, K, lda, ldb, ldc, sA, sB, sC, alpha, gx, gy);
    } else {
        if (relu) gemm4_bf16<MR, NR, false, true ><<<grid, 512, 0, st>>>(A, BT, bias, C, M, N, K, lda, ldb, ldc, sA, sB, sC, alpha, gx, gy);
        else      gemm4_bf16<MR, NR, false, false><<<grid, 512, 0, st>>>(A, BT, bias, C, M, N, K, lda, ldb, ldc, sA, sB, sC, alpha, gx, gy);
    }
}

// ---------------------------------------------------------------------------
// old m97-structure engine, kept for the small batched GEMMs (scores, PV)
// ---------------------------------------------------------------------------
template<int BM, int BN, bool OUT_BF16>
__global__ __launch_bounds__(256)
void gemm_bf16(const unsigned short* __restrict__ A,
               const unsigned short* __restrict__ BT,
               const float* __restrict__ bias, void* __restrict__ Cv,
               int M, int N, int K, int lda, int ldb, int ldc,
               long long sA, long long sB, long long sC, float alpha,
               int gx, int gy)
{
    constexpr int BK = 32;
    constexpr int WM = BM / 2, WN = BN / 2;
    constexpr int MR = WM / 16, NR = WN / 16;
    __shared__ unsigned short Asm[BM * BK];
    __shared__ unsigned short Bsm[BN * BK];

    A  += (long long)blockIdx.z * sA;
    BT += (long long)blockIdx.z * sB;
    char* Cb = (char*)Cv + (long long)blockIdx.z * sC * (OUT_BF16 ? 2 : 4);

    const int nwg = gx * gy;
    int orig = blockIdx.x;
    int xcd = orig & 7, sidx = orig >> 3;
    int qq = nwg >> 3, rr = nwg & 7;
    int wg = (xcd < rr ? xcd * (qq + 1) : rr * (qq + 1) + (xcd - rr) * qq) + sidx;
    const int row0 = (wg % gy) * BM;
    const int col0 = (wg / gy) * BN;

    const int tid  = threadIdx.x;
    const int lane = tid & 63;
    const int wave = tid >> 6;
    const int wr   = wave >> 1;
    const int wc   = wave & 1;

    const int srow = tid >> 2;
    const int skel = (tid & 3) * 8;

    f32x4 acc[MR][NR] = {};

    const int lrow = lane & 15;
    const int lk   = (lane >> 4) * 8;

    for (int k0 = 0; k0 < K; k0 += BK) {
        #pragma unroll
        for (int is = 0; is < BM / 64; ++is)
            GLOAD_LDS16(A + (long long)(row0 + is * 64 + srow) * lda + (k0 + skel),
                        &Asm[(is * 64 + srow) * BK + skel]);
        #pragma unroll
        for (int is = 0; is < BN / 64; ++is)
            GLOAD_LDS16(BT + (long long)(col0 + is * 64 + srow) * ldb + (k0 + skel),
                        &Bsm[(is * 64 + srow) * BK + skel]);
        __syncthreads();

        bf16x8 af[MR], bfr[NR];
        #pragma unroll
        for (int mf = 0; mf < MR; ++mf)
            af[mf] = *(const bf16x8*)&Asm[(wr * WM + mf * 16 + lrow) * BK + lk];
        #pragma unroll
        for (int nf = 0; nf < NR; ++nf)
            bfr[nf] = *(const bf16x8*)&Bsm[(wc * WN + nf * 16 + lrow) * BK + lk];
        #pragma unroll
        for (int mf = 0; mf < MR; ++mf)
            #pragma unroll
            for (int nf = 0; nf < NR; ++nf)
                acc[mf][nf] = __builtin_amdgcn_mfma_f32_16x16x32_bf16(
                    af[mf], bfr[nf], acc[mf][nf], 0, 0, 0);
        __syncthreads();
    }

    const int crow = (lane >> 4) * 4;
    const int ccol = lane & 15;
    #pragma unroll
    for (int mf = 0; mf < MR; ++mf) {
        int rbase = row0 + wr * WM + mf * 16 + crow;
        #pragma unroll
        for (int nf = 0; nf < NR; ++nf) {
            int c = col0 + wc * WN + nf * 16 + ccol;
            if (c >= N) continue;
            float bv = bias ? bias[c] : 0.f;
            #pragma unroll
            for (int j = 0; j < 4; ++j) {
                int r = rbase + j;
                if (r >= M) continue;
                float v = acc[mf][nf][j] * alpha + bv;
                if (OUT_BF16)
                    ((unsigned short*)Cb)[(long long)r * ldc + c] = f2bf(v);
                else
                    ((float*)Cb)[(long long)r * ldc + c] = v;
            }
        }
    }
}

template<int BM, int BN>
static void gemm_t(bool outBf16,
                   const unsigned short* A, const unsigned short* BT, const float* bias,
                   void* C, int M, int N, int K, int lda, int ldb, int ldc,
                   int batch, long long sA, long long sB, long long sC,
                   float alpha, hipStream_t st)
{
    int gx = (N + BN - 1) / BN, gy = (M + BM - 1) / BM;
    dim3 grid(gx * gy, 1, batch);
    if (outBf16)
        gemm_bf16<BM, BN, true ><<<grid, 256, 0, st>>>(A, BT, bias, C, M, N, K, lda, ldb, ldc, sA, sB, sC, alpha, gx, gy);
    else
        gemm_bf16<BM, BN, false><<<grid, 256, 0, st>>>(A, BT, bias, C, M, N, K, lda, ldb, ldc, sA, sB, sC, alpha, gx, gy);
}

// ---------------------------------------------------------------------------
// split-K reduce + bias + residual(x) + whole-norm stats (r12-proven,
// two-kernel chain: NO inter-block communication, deterministic)
// ---------------------------------------------------------------------------
__global__ void splitk_stats_kernel(const float4* __restrict__ part,
                                    const float4* __restrict__ bias,
                                    const float4* __restrict__ x,
                                    float4* __restrict__ z,
                                    double* __restrict__ dpart,
                                    long long n4, int N4, int nsplit, long long stride4)
{
    __shared__ double rs[256], rs2[256];
    int tid = threadIdx.x;
    long long i = (long long)blockIdx.x * blockDim.x + tid;
    long long gs = (long long)gridDim.x * blockDim.x;
    double s = 0.0, s2 = 0.0;
    for (; i < n4; i += gs) {
        float4 a = part[i];
        for (int sp = 1; sp < nsplit; ++sp) {
            float4 b = part[(long long)sp * stride4 + i];
            a.x += b.x; a.y += b.y; a.z += b.z; a.w += b.w;
        }
        float4 bv = bias[(int)(i % N4)];
        float4 xv = x[i];
        a.x += bv.x + xv.x; a.y += bv.y + xv.y; a.z += bv.z + xv.z; a.w += bv.w + xv.w;
        z[i] = a;
        s  += (double)a.x + (double)a.y + (double)a.z + (double)a.w;
        s2 += (double)a.x * a.x + (double)a.y * a.y + (double)a.z * a.z + (double)a.w * a.w;
    }
    rs[tid] = s; rs2[tid] = s2; __syncthreads();
    for (int k = 128; k > 0; k >>= 1) {
        if (tid < k) { rs[tid] += rs[tid + k]; rs2[tid] += rs2[tid + k]; }
        __syncthreads();
    }
    if (tid == 0) { dpart[2 * blockIdx.x] = rs[0]; dpart[2 * blockIdx.x + 1] = rs2[0]; }
}

__global__ void stats_kernel(const float4* __restrict__ a, const float4* __restrict__ f,
                             double* __restrict__ part, long long n4)
{
    __shared__ double rs[256], rs2[256];
    int tid = threadIdx.x;
    long long i = (long long)blockIdx.x * blockDim.x + tid;
    long long stride = (long long)gridDim.x * blockDim.x;
    double s = 0.0, s2 = 0.0;
    for (; i < n4; i += stride) {
        float4 av = a[i], fv = f[i];
        float z0 = av.x + fv.x, z1 = av.y + fv.y, z2 = av.z + fv.z, z3 = av.w + fv.w;
        s  += (double)z0 + (double)z1 + (double)z2 + (double)z3;
        s2 += (double)z0 * z0 + (double)z1 * z1 + (double)z2 * z2 + (double)z3 * z3;
    }
    rs[tid] = s; rs2[tid] = s2; __syncthreads();
    for (int k = 128; k > 0; k >>= 1) {
        if (tid < k) { rs[tid] += rs[tid + k]; rs2[tid] += rs2[tid + k]; }
        __syncthreads();
    }
    if (tid == 0) { part[2 * blockIdx.x] = rs[0]; part[2 * blockIdx.x + 1] = rs2[0]; }
}

__global__ void finish_stats(const double* __restrict__ part, int npart,
                             float* __restrict__ stats, double n)
{
    __shared__ double rs[256], rs2[256];
    int tid = threadIdx.x;
    double s = 0.0, s2 = 0.0;
    for (int i = tid; i < npart; i += 256) { s += part[2 * i]; s2 += part[2 * i + 1]; }
    rs[tid] = s; rs2[tid] = s2; __syncthreads();
    for (int k = 128; k > 0; k >>= 1) {
        if (tid < k) { rs[tid] += rs[tid + k]; rs2[tid] += rs2[tid + k]; }
        __syncthreads();
    }
    if (tid == 0) {
        double mu  = rs[0] / n;
        double var = rs2[0] / n - mu * mu;
        stats[0] = (float)mu;
        stats[1] = (float)(1.0 / sqrt(var + 1e-6));
    }
}

// norm apply recomputing z = a + f, bf16 out (norm1 -> y1)
__global__ void norm_apply_kernel(const float4* __restrict__ a, const float4* __restrict__ f,
                                  const float4* __restrict__ nw, const float4* __restrict__ nb,
                                  const float* __restrict__ stats, ushort4* __restrict__ out,
                                  long long n4)
{
    float mu = stats[0], rstd = stats[1];
    long long i = (long long)blockIdx.x * blockDim.x + threadIdx.x;
    long long stride = (long long)gridDim.x * blockDim.x;
    for (; i < n4; i += stride) {
        float4 av = a[i], fv = f[i], wv = nw[i], bv = nb[i];
        ushort4 o;
        o.x = f2bf((av.x + fv.x - mu) * rstd * wv.x + bv.x);
        o.y = f2bf((av.y + fv.y - mu) * rstd * wv.y + bv.y);
        o.z = f2bf((av.z + fv.z - mu) * rstd * wv.z + bv.z);
        o.w = f2bf((av.w + fv.w - mu) * rstd * wv.w + bv.w);
        out[i] = o;
    }
}

// norm apply reading z directly (z already includes residual), fp32 out
__global__ void norm_apply_z_kernel(const float4* __restrict__ z,
                                    const float4* __restrict__ nw, const float4* __restrict__ nb,
                                    const float* __restrict__ stats, float4* __restrict__ out,
                                    long long n4)
{
    float mu = stats[0], rstd = stats[1];
    long long i = (long long)blockIdx.x * blockDim.x + threadIdx.x;
    long long stride = (long long)gridDim.x * blockDim.x;
    for (; i < n4; i += stride) {
        float4 zv = z[i], wv = nw[i], bv = nb[i];
        float4 o;
        o.x = (zv.x - mu) * rstd * wv.x + bv.x;
        o.y = (zv.y - mu) * rstd * wv.y + bv.y;
        o.z = (zv.z - mu) * rstd * wv.z + bv.z;
        o.w = (zv.w - mu) * rstd * wv.w + bv.w;
        out[i] = o;
    }
}

// ---------------------------------------------------------------------------
// elementwise cast f32 -> bf16
// ---------------------------------------------------------------------------
__global__ void cast_bf16_kernel(const float4* __restrict__ in,
                                 ushort4* __restrict__ out, long long n4)
{
    long long i = (long long)blockIdx.x * blockDim.x + threadIdx.x;
    long long stride = (long long)gridDim.x * blockDim.x;
    for (; i < n4; i += stride) {
        float4 v = in[i];
        ushort4 o;
        o.x = f2bf(v.x); o.y = f2bf(v.y); o.z = f2bf(v.z); o.w = f2bf(v.w);
        out[i] = o;
    }
}

// concat bias: out = [bq | bk | bv]  (pure data-parallel, no cross-block dep)
__global__ void concat_bias_kernel(const float* __restrict__ bq, const float* __restrict__ bk,
                                   const float* __restrict__ bv, float* __restrict__ out, int D)
{
    int i = blockIdx.x * 256 + threadIdx.x;
    if (i < D) { out[i] = bq[i]; out[D + i] = bk[i]; out[2 * D + i] = bv[i]; }
}

// ---------------------------------------------------------------------------
// transpose + cast: src f32 [R,C] -> dst bf16 [C, Rpad]
// ---------------------------------------------------------------------------
__global__ void transpose_cast_kernel(const float* __restrict__ src,
                                      unsigned short* __restrict__ dst,
                                      int R, int C, int Rpad,
                                      long long sSrc, long long sDst)
{
    __shared__ float t[32][33];
    src += (long long)blockIdx.z * sSrc;
    dst += (long long)blockIdx.z * sDst;
    int r0 = blockIdx.x * 32, c0 = blockIdx.y * 32;
    int tx = threadIdx.x & 31, ty = threadIdx.x >> 5;
    #pragma unroll
    for (int i = 0; i < 32; i += 8) {
        int r = r0 + ty + i, c = c0 + tx;
        t[ty + i][tx] = (r < R && c < C) ? src[(long long)r * C + c] : 0.f;
    }
    __syncthreads();
    #pragma unroll
    for (int i = 0; i < 32; i += 8) {
        int c = c0 + ty + i, r = r0 + tx;
        if (c < C && r < Rpad)
            dst[(long long)c * Rpad + r] = f2bf(t[tx][ty + i]);
    }
}

// three same-shape square transposes in one launch (QKV weights), z selects
__global__ void transpose_cast3_kernel(const float* __restrict__ s0,
                                       const float* __restrict__ s1,
                                       const float* __restrict__ s2,
                                       unsigned short* __restrict__ dst, int D)
{
    __shared__ float t[32][33];
    const float* src = blockIdx.z == 0 ? s0 : (blockIdx.z == 1 ? s1 : s2);
    dst += (long long)blockIdx.z * D * D;
    int r0 = blockIdx.x * 32, c0 = blockIdx.y * 32;
    int tx = threadIdx.x & 31, ty = threadIdx.x >> 5;
    #pragma unroll
    for (int i = 0; i < 32; i += 8)
        t[ty + i][tx] = src[(long long)(r0 + ty + i) * D + (c0 + tx)];
    __syncthreads();
    #pragma unroll
    for (int i = 0; i < 32; i += 8)
        dst[(long long)(c0 + ty + i) * D + (r0 + tx)] = f2bf(t[tx][ty + i]);
}

// transpose bf16 [R,C] (row stride ldS) -> bf16 [C, Rpad]
__global__ void transpose_bf16_kernel(const unsigned short* __restrict__ src,
                                      unsigned short* __restrict__ dst,
                                      int R, int C, int Rpad, int ldS,
                                      long long sSrc, long long sDst)
{
    __shared__ unsigned short t[32][33];
    src += (long long)blockIdx.z * sSrc;
    dst += (long long)blockIdx.z * sDst;
    int r0 = blockIdx.x * 32, c0 = blockIdx.y * 32;
    int tx = threadIdx.x & 31, ty = threadIdx.x >> 5;
    #pragma unroll
    for (int i = 0; i < 32; i += 8) {
        int r = r0 + ty + i, c = c0 + tx;
        t[ty + i][tx] = (r < R && c < C) ? src[(long long)r * ldS + c] : (unsigned short)0;
    }
    __syncthreads();
    #pragma unroll
    for (int i = 0; i < 32; i += 8) {
        int c = c0 + ty + i, r = r0 + tx;
        if (c < C && r < Rpad)
            dst[(long long)c * Rpad + r] = t[tx][ty + i];
    }
}

// ---------------------------------------------------------------------------
// Ktot two-stage deterministic reduction over s (bf16 input, strided ld)
// ---------------------------------------------------------------------------
#define KTOT_NCH 16
__global__ void ktot_partial_bf16(const unsigned short* __restrict__ k,
                                  float* __restrict__ part,
                                  int B, int S, int D, int ld)
{
    int bch = blockIdx.x;
    int b  = bch / KTOT_NCH;
    int ch = bch % KTOT_NCH;
    int d  = blockIdx.y * 256 + threadIdx.x;
    if (d >= D) return;
    int len = (S + KTOT_NCH - 1) / KTOT_NCH;
    int lo = ch * len;
    int hi = lo + len < S ? lo + len : S;
    const unsigned short* kp = k + ((long long)b * S + lo) * ld + d;
    float s = 0.f;
    for (int t = lo; t < hi; ++t, kp += ld) s += bf2f(*kp);
    part[(long long)bch * D + d] = s;
}

__global__ void ktot_finish_kernel(const float* __restrict__ part,
                                   float* __restrict__ ktot, int B, int D)
{
    int idx = blockIdx.x * blockDim.x + threadIdx.x;
    if (idx >= B * D) return;
    int b = idx / D, d = idx % D;
    float s = 0.f;
    #pragma unroll
    for (int ch = 0; ch < KTOT_NCH; ++ch)
        s += part[((long long)b * KTOT_NCH + ch) * D + d];
    ktot[idx] = s;
}

// ---------------------------------------------------------------------------
// kk[b,s,d] = (Ktot[b,d] + (e-1)*window_sum) / Z_s  from bf16 k (stride ld)
// ---------------------------------------------------------------------------
__global__ void kk_bf16_kernel(const unsigned short* __restrict__ k,
                               const float* __restrict__ ktot,
                               unsigned short* __restrict__ kk,
                               int B, int S, int D, int ld)
{
    long long idx = (long long)blockIdx.x * blockDim.x + threadIdx.x;
    int D4 = D >> 2;
    long long n4 = (long long)B * S * D4;
    if (idx >= n4) return;
    int d4 = (int)(idx % D4);
    long long bs = idx / D4;
    int s = (int)(bs % S);
    int b = (int)(bs / S);
    int lo = s - 2 > 0 ? s - 2 : 0;
    int hi = s + 2 < S - 1 ? s + 2 : S - 1;
    int c = hi - lo + 1;
    const float E = 2.718281828459045f;
    float Zinv = 1.f / ((float)(S - c) + E * (float)c);

    float w0 = 0.f, w1 = 0.f, w2 = 0.f, w3 = 0.f;
    const unsigned short* kp = k + ((long long)b * S + lo) * ld + d4 * 4;
    for (int t = lo; t <= hi; ++t, kp += ld) {
        ushort4 kv = *(const ushort4*)kp;
        w0 += bf2f(kv.x); w1 += bf2f(kv.y); w2 += bf2f(kv.z); w3 += bf2f(kv.w);
    }
    float4 tot = *((const float4*)(ktot + b * D) + d4);
    ushort4 o;
    o.x = f2bf((tot.x + (E - 1.f) * w0) * Zinv);
    o.y = f2bf((tot.y + (E - 1.f) * w1) * Zinv);
    o.z = f2bf((tot.z + (E - 1.f) * w2) * Zinv);
    o.w = f2bf((tot.w + (E - 1.f) * w3) * Zinv);
    ((ushort4*)(kk + ((long long)b * S + s) * D))[d4] = o;
}

// ---------------------------------------------------------------------------
// row softmax: fp32 scores [rows][Spad] -> bf16 P, pads = 0.
// Register-cached: one read pass (values), exp computed once, one write pass.
// Requires S <= 512 and Spad <= 512 (text 512/512, image 196/224).
// ---------------------------------------------------------------------------
__global__ void softmax_rows_bf16(const float* __restrict__ sc,
                                  unsigned short* __restrict__ P, int S, int Spad)
{
    long long row = blockIdx.x;
    const float* p = sc + row * (long long)Spad;
    unsigned short* o = P + row * (long long)Spad;
    int tid = threadIdx.x;
    __shared__ float red[256];

    float v0 = (tid < S)       ? p[tid]       : -INFINITY;
    float v1 = (tid + 256 < S) ? p[tid + 256] : -INFINITY;

    float m = fmaxf(v0, v1);
    red[tid] = m; __syncthreads();
    for (int s = 128; s > 0; s >>= 1) {
        if (tid < s) red[tid] = fmaxf(red[tid], red[tid + s]);
        __syncthreads();
    }
    m = red[0];
    __syncthreads();

    float e0 = (tid < S)       ? __expf(v0 - m) : 0.f;
    float e1 = (tid + 256 < S) ? __expf(v1 - m) : 0.f;
    red[tid] = e0 + e1; __syncthreads();
    for (int s = 128; s > 0; s >>= 1) {
        if (tid < s) red[tid] += red[tid + s];
        __syncthreads();
    }
    float inv = 1.f / red[0];

    if (tid < Spad)       o[tid]       = (tid < S)       ? f2bf(e0 * inv) : (unsigned short)0;
    if (tid + 256 < Spad) o[tid + 256] = (tid + 256 < S) ? f2bf(e1 * inv) : (unsigned short)0;
}

// ---------------------------------------------------------------------------
// host-side orchestration
// ---------------------------------------------------------------------------
struct Bufs {
    unsigned short *xb, *qkv, *kkb, *vT, *P, *h, *WqkvT, *W1T, *W2T;
    float *f32buf, *bqkv, *ktot, *ktot_part, *stats;
    double *part;
};

static void run_branch(const float* x, const float* const* w, bool big,
                       float* out, int B, int S, int D, const Bufs& wsb, hipStream_t st)
{
    const float *Wq = w[0], *bq = w[1], *Wk = w[2], *bk = w[3], *Wv = w[4], *bv = w[5];
    const float *W1 = w[6], *b1 = w[7], *W2 = w[8], *b2 = w[9], *nw = w[10], *nb = w[11];

    const int Spad = (S + 31) & ~31;
    const long long M = (long long)B * S;
    const long long n = M * D;
    const long long n4 = n / 4;
    const float inv_sqrt_d = (float)(1.0 / sqrt((double)D));
    const int D3 = 3 * D, D4 = 4 * D;

    unsigned short* y1b = wsb.kkb;           // alias: kkb dead after scores GEMM
    float* scores = (float*)wsb.h;           // alias: h free until FFN1
    float* splitbuf = (float*)wsb.qkv;       // alias: qkv+kkb+vT dead during FFN2

    // casts: x -> xb ; weights -> transposed bf16 (QKV concat), bias concat
    cast_bf16_kernel<<<1024, 256, 0, st>>>((const float4*)x, (ushort4*)wsb.xb, n4);
    transpose_cast3_kernel<<<dim3(D / 32, D / 32, 3), 256, 0, st>>>(Wq, Wk, Wv, wsb.WqkvT, D);
    transpose_cast_kernel<<<dim3((D + 31) / 32, (D4 + 31) / 32, 1), 256, 0, st>>>(W1, wsb.W1T, D, D4, D, 0, 0);
    transpose_cast_kernel<<<dim3((D4 + 31) / 32, (D + 31) / 32, 1), 256, 0, st>>>(W2, wsb.W2T, D4, D, D4, 0, 0);
    concat_bias_kernel<<<(D + 255) / 256, 256, 0, st>>>(bq, bk, bv, wsb.bqkv, D);

    // fused QKV: [M,3D] bf16 (gemm4 128x128)
    gemm4_t<4, 2>(true, false, wsb.xb, wsb.WqkvT, wsb.bqkv, wsb.qkv,
                  (int)M, D3, D, D, D, D3, 1, 0, 0, 0, 1.f, st);

    // kk = softmax(band mask) @ k  (analytic, bf16 k at column offset D)
    const unsigned short* kcol = wsb.qkv + D;
    ktot_partial_bf16<<<dim3(B * KTOT_NCH, (D + 255) / 256), 256, 0, st>>>(kcol, wsb.ktot_part, B, S, D, D3);
    ktot_finish_kernel<<<(B * D + 255) / 256, 256, 0, st>>>(wsb.ktot_part, wsb.ktot, B, D);
    kk_bf16_kernel<<<(int)((n4 + 255) / 256), 256, 0, st>>>(kcol, wsb.ktot, wsb.kkb, B, S, D, D3);

    // vT bf16 [B][D][Spad]  (v at column offset 2D)
    transpose_bf16_kernel<<<dim3((Spad + 31) / 32, (D + 31) / 32, B), 256, 0, st>>>(
        wsb.qkv + 2 * D, wsb.vT, S, D, Spad, D3, (long long)S * D3, (long long)D * Spad);

    // scores = q @ kk^T / sqrt(D)
    gemm_t<64, 64>(false, wsb.qkv, wsb.kkb, nullptr, scores, S, S, D, D3, D, Spad,
                   B, (long long)S * D3, (long long)S * D, (long long)S * Spad, inv_sqrt_d, st);
    softmax_rows_bf16<<<(int)M, 256, 0, st>>>(scores, wsb.P, S, Spad);

    // attn = P @ v -> f32buf
    gemm_t<128, 64>(false, wsb.P, wsb.vT, nullptr, wsb.f32buf, S, D, Spad, Spad, Spad, D,
                    B, (long long)S * Spad, (long long)D * Spad, (long long)S * D, 1.f, st);

    // norm1: y1 = whole_norm(attn + x) -> bf16 (into kkb region)
    stats_kernel<<<1024, 256, 0, st>>>((const float4*)wsb.f32buf, (const float4*)x, wsb.part, n4);
    finish_stats<<<1, 256, 0, st>>>(wsb.part, 1024, wsb.stats, (double)n);
    norm_apply_kernel<<<2048, 256, 0, st>>>((const float4*)wsb.f32buf, (const float4*)x,
        (const float4*)nw, (const float4*)nb, wsb.stats, (ushort4*)y1b, n4);

    // FFN1 -> h (bf16, relu), gemm4 128x128
    gemm4_t<4, 2>(true, true, y1b, wsb.W1T, b1, wsb.h, (int)M, D4, D, D, D, D4, 1, 0, 0, 0, 1.f, st);

    // FFN2 split-K -> partials (fp32), reduce+bias+residual+stats, finish, apply
    {
        int nsplit = big ? 2 : 8;
        int Ksp = D4 / nsplit;
        gemm4_t<4, 2>(false, false, wsb.h, wsb.W2T, nullptr, splitbuf,
                      (int)M, D, Ksp, D4, D4, D,
                      nsplit, Ksp, Ksp, M * D, 1.f, st);
        splitk_stats_kernel<<<1024, 256, 0, st>>>((const float4*)splitbuf, (const float4*)b2,
                                                  (const float4*)x, (float4*)wsb.f32buf,
                                                  wsb.part, n4, D / 4, nsplit, n4);
        finish_stats<<<1, 256, 0, st>>>(wsb.part, 1024, wsb.stats, (double)n);
        norm_apply_z_kernel<<<2048, 256, 0, st>>>((const float4*)wsb.f32buf,
            (const float4*)nw, (const float4*)nb, wsb.stats, (float4*)out, n4);
    }
}

extern "C" void kernel_launch(void* const* d_in, const int* in_sizes, int n_in,
                              void* d_out, int out_size, void* d_ws, size_t ws_size,
                              hipStream_t stream)
{
    const float* text  = (const float*)d_in[0];
    const float* image = (const float*)d_in[1];
    const float* tw[12];
    const float* iw[12];
    for (int i = 0; i < 12; ++i) tw[i] = (const float*)d_in[2 + i];
    for (int i = 0; i < 12; ++i) iw[i] = (const float*)d_in[14 + i];

    float* out_text = (float*)d_out;                 // [8,512,1024]
    float* out_img  = out_text + 8LL * 512 * 1024;   // [8,196,768]

    // workspace layout (text-branch sizes; image reuses)
    char* p = (char*)d_ws;
    auto alloc = [&](long long bytes) {
        char* r = p;
        p += (bytes + 255) & ~255LL;
        return r;
    };
    const long long MD  = 4096LL * 1024;    // B*S*D
    const long long BDS = 8LL * 1024 * 512; // B*D*Spad
    const long long SS  = 8LL * 512 * 512;  // B*S*Spad
    Bufs b;
    b.xb      = (unsigned short*)alloc(MD * 2);          // 8 MB
    b.qkv     = (unsigned short*)alloc(MD * 3 * 2);      // 24 MB (splitbuf lo)
    b.kkb     = (unsigned short*)alloc(MD * 2);          // 8 MB (y1b, splitbuf mid)
    b.vT      = (unsigned short*)alloc(BDS * 2);         // 8 MB (splitbuf hi, image)
    b.P       = (unsigned short*)alloc(SS * 2);          // 4 MB
    b.h       = (unsigned short*)alloc(MD * 4 * 2);      // 32 MB (also scores)
    b.WqkvT   = (unsigned short*)alloc(3LL * 1024 * 1024 * 2);  // 6 MB
    b.W1T     = (unsigned short*)alloc(4096LL * 1024 * 2);      // 8 MB
    b.W2T     = (unsigned short*)alloc(4096LL * 1024 * 2);      // 8 MB
    b.f32buf  = (float*)alloc(MD * 4);                   // 16 MB
    b.bqkv    = (float*)alloc(3LL * 1024 * 4);
    b.ktot    = (float*)alloc(8192LL * 4);
    b.ktot_part = (float*)alloc(8192LL * KTOT_NCH * 4);
    b.part    = (double*)alloc(2048LL * 8);
    b.stats   = (float*)alloc(256);

    run_branch(text,  tw, true,  out_text, 8, 512, 1024, b, stream);
    run_branch(image, iw, false, out_img,  8, 196, 768,  b, stream);
}

// Round 20
// 430.623 us; speedup vs baseline: 1.1851x; 1.0010x over previous
//
#include <hip/hip_runtime.h>
#include <math.h>

typedef float  f32x4  __attribute__((ext_vector_type(4)));
typedef short  bf16x8 __attribute__((ext_vector_type(8)));

__device__ __forceinline__ unsigned short f2bf(float f) {
    union { float f; unsigned u; } v; v.f = f;
    unsigned u = v.u;
    return (unsigned short)((u + 0x7FFFu + ((u >> 16) & 1u)) >> 16);
}
__device__ __forceinline__ float bf2f(unsigned short u) {
    union { unsigned u; float f; } v; v.u = (unsigned)u << 16; return v.f;
}

#define GLOAD_LDS16(g, l)                                                      \
    __builtin_amdgcn_global_load_lds(                                          \
        (const __attribute__((address_space(1))) void*)(g),                    \
        (__attribute__((address_space(3))) void*)(l), 16, 0, 0)

// ---------------------------------------------------------------------------
// gemm4 (r12/r18-verified best): 128x128 tile (MR=4,NR=2), BK=64, 8 waves,
// 2 LDS dbuf (64 KB -> 2 blocks/CU), stage-first + one barrier/K-tile,
// both-sides XOR swizzle (0 bank conflicts, verified r11/r12), setprio.
// A: bf16 [M,K] lda; BT: bf16 [N,K] ldb; C: fp32 or bf16, ldc.
// Batched via blockIdx.z. K%64==0. A-staging may over-read rows past M
// (workspace buffers have slack); C-writes are guarded.
// ---------------------------------------------------------------------------
template<int MR, int NR, bool OUT_BF16, bool RELU>
__global__ __launch_bounds__(512, 4)
void gemm4_bf16(const unsigned short* __restrict__ A,
                const unsigned short* __restrict__ BT,
                const float* __restrict__ bias, void* __restrict__ Cv,
                int M, int N, int K, int lda, int ldb, int ldc,
                long long sA, long long sB, long long sC, float alpha,
                int gx, int gy)
{
    constexpr int BK = 64;
    constexpr int WM = MR * 16, WN = NR * 16;
    constexpr int BM = 2 * WM, BN = 4 * WN;
    __shared__ unsigned short Asm[2][BM * BK];
    __shared__ unsigned short Bsm[2][BN * BK];

    A  += (long long)blockIdx.z * sA;
    BT += (long long)blockIdx.z * sB;
    char* Cb = (char*)Cv + (long long)blockIdx.z * sC * (OUT_BF16 ? 2 : 4);

    // bijective XCD swizzle (m204); n-fastest within each XCD chunk
    const int nwg = gx * gy;
    int orig = blockIdx.x;
    int xcd = orig & 7, sidx = orig >> 3;
    int qq = nwg >> 3, rr = nwg & 7;
    int wg = (xcd < rr ? xcd * (qq + 1) : rr * (qq + 1) + (xcd - rr) * qq) + sidx;
    const int row0 = (wg / gx) * BM;
    const int col0 = (wg % gx) * BN;

    const int tid  = threadIdx.x;
    const int lane = tid & 63;
    const int wave = tid >> 6;
    const int wr   = wave >> 2;
    const int wc   = wave & 3;

    const int lrow = lane & 15;
    const int cgrp = lane >> 4;

    f32x4 acc[MR][NR] = {};

    // staging: 512 thr x 16B = 8 KB = 64 rows x 128 B per issue; linear LDS
    // dest, source chunk pre-swizzled: LDS physical chunk p at row r holds
    // logical chunk p^(r&7).   [both-sides swizzle, verified r11/r12]
    const int srl = tid >> 3;
    const int scl = (tid & 7) ^ (srl & 7);

    auto stage = [&](int buf, int k0) {
        #pragma unroll
        for (int is = 0; is < BM / 64; ++is)
            GLOAD_LDS16(A + (long long)(row0 + is * 64 + srl) * lda + (k0 + scl * 8),
                        &Asm[buf][is * 64 * BK + tid * 8]);
        #pragma unroll
        for (int is = 0; is < BN / 64; ++is)
            GLOAD_LDS16(BT + (long long)(col0 + is * 64 + srl) * ldb + (k0 + scl * 8),
                        &Bsm[buf][is * 64 * BK + tid * 8]);
    };

    const int nt = K / BK;
    stage(0, 0);
    __syncthreads();

    for (int t = 0; t < nt; ++t) {
        if (t + 1 < nt) stage((t + 1) & 1, (t + 1) * BK);
        const int cur = t & 1;

        bf16x8 a_[2][MR], b_[2][NR];
        #pragma unroll
        for (int kk = 0; kk < 2; ++kk) {
            #pragma unroll
            for (int mf = 0; mf < MR; ++mf) {
                int row = wr * WM + mf * 16 + lrow;
                int phys = (kk * 4 + cgrp) ^ (row & 7);
                a_[kk][mf] = *(const bf16x8*)&Asm[cur][row * BK + phys * 8];
            }
            #pragma unroll
            for (int nf = 0; nf < NR; ++nf) {
                int row = wc * WN + nf * 16 + lrow;
                int phys = (kk * 4 + cgrp) ^ (row & 7);
                b_[kk][nf] = *(const bf16x8*)&Bsm[cur][row * BK + phys * 8];
            }
        }

        __builtin_amdgcn_s_setprio(1);
        #pragma unroll
        for (int kk = 0; kk < 2; ++kk)
            #pragma unroll
            for (int mf = 0; mf < MR; ++mf)
                #pragma unroll
                for (int nf = 0; nf < NR; ++nf)
                    acc[mf][nf] = __builtin_amdgcn_mfma_f32_16x16x32_bf16(
                        a_[kk][mf], b_[kk][nf], acc[mf][nf], 0, 0, 0);
        __builtin_amdgcn_s_setprio(0);

        __syncthreads();
    }

    // C/D layout: col = lane&15, row = (lane>>4)*4 + j   [m89 verified]
    const int crow = cgrp * 4;
    const int ccol = lane & 15;
    #pragma unroll
    for (int mf = 0; mf < MR; ++mf) {
        int rbase = row0 + wr * WM + mf * 16 + crow;
        #pragma unroll
        for (int nf = 0; nf < NR; ++nf) {
            int c = col0 + wc * WN + nf * 16 + ccol;
            if (c >= N) continue;
            float bv = bias ? bias[c] : 0.f;
            #pragma unroll
            for (int j = 0; j < 4; ++j) {
                int r = rbase + j;
                if (r >= M) continue;
                float v = acc[mf][nf][j] * alpha + bv;
                if (RELU) v = fmaxf(v, 0.f);
                if (OUT_BF16)
                    ((unsigned short*)Cb)[(long long)r * ldc + c] = f2bf(v);
                else
                    ((float*)Cb)[(long long)r * ldc + c] = v;
            }
        }
    }
}

template<int MR, int NR>
static void gemm4_t(bool outBf16, bool relu,
                    const unsigned short* A, const unsigned short* BT, const float* bias,
                    void* C, int M, int N, int K, int lda, int ldb, int ldc,
                    int batch, long long sA, long long sB, long long sC,
                    float alpha, hipStream_t st)
{
    const int BM = 2 * MR * 16, BN = 4 * NR * 16;
    int gx = (N + BN - 1) / BN, gy = (M + BM - 1) / BM;
    dim3 grid(gx * gy, 1, batch);
    if (outBf16) {
        if (relu) gemm4_bf16<MR, NR, true , true ><<<grid, 512, 0, st>>>(A, BT, bias, C, M, N, K, lda, ldb, ldc, sA, sB, sC, alpha, gx, gy);
        else      gemm4_bf16<MR, NR, true , false><<<grid, 512, 0, st>>>(A, BT, bias, C, M, N, K, lda, ldb, ldc, sA, sB, sC, alpha, gx, gy);
    } else {
        if (relu) gemm4_bf16<MR, NR, false, true ><<<grid, 512, 0, st>>>(A, BT, bias, C, M, N, K, lda, ldb, ldc, sA, sB, sC, alpha, gx, gy);
        else      gemm4_bf16<MR, NR, false, false><<<grid, 512, 0, st>>>(A, BT, bias, C, M, N, K, lda, ldb, ldc, sA, sB, sC, alpha, gx, gy);
    }
}

// ---------------------------------------------------------------------------
// old m97-structure engine (scores, PV) — now with the both-sides XOR swizzle
// at BK=32: source col chunk ^ ((srow>>1)&3), read phys cgrp ^ ((row>>1)&3).
// Banks per 16-lane quarter-wave: 8-way -> 2-way (free, m136).
// ---------------------------------------------------------------------------
template<int BM, int BN, bool OUT_BF16>
__global__ __launch_bounds__(256)
void gemm_bf16(const unsigned short* __restrict__ A,
               const unsigned short* __restrict__ BT,
               const float* __restrict__ bias, void* __restrict__ Cv,
               int M, int N, int K, int lda, int ldb, int ldc,
               long long sA, long long sB, long long sC, float alpha,
               int gx, int gy)
{
    constexpr int BK = 32;
    constexpr int WM = BM / 2, WN = BN / 2;
    constexpr int MR = WM / 16, NR = WN / 16;
    __shared__ unsigned short Asm[BM * BK];
    __shared__ unsigned short Bsm[BN * BK];

    A  += (long long)blockIdx.z * sA;
    BT += (long long)blockIdx.z * sB;
    char* Cb = (char*)Cv + (long long)blockIdx.z * sC * (OUT_BF16 ? 2 : 4);

    const int nwg = gx * gy;
    int orig = blockIdx.x;
    int xcd = orig & 7, sidx = orig >> 3;
    int qq = nwg >> 3, rr = nwg & 7;
    int wg = (xcd < rr ? xcd * (qq + 1) : rr * (qq + 1) + (xcd - rr) * qq) + sidx;
    const int row0 = (wg % gy) * BM;
    const int col0 = (wg / gy) * BN;

    const int tid  = threadIdx.x;
    const int lane = tid & 63;
    const int wave = tid >> 6;
    const int wr   = wave >> 1;
    const int wc   = wave & 1;

    const int srow = tid >> 2;                         // 0..63 row in issue grp
    const int skel = (tid & 3) * 8;                    // linear LDS dest chunk
    const int sswz = ((tid & 3) ^ ((srow >> 1) & 3)) * 8;  // pre-swz source col

    f32x4 acc[MR][NR] = {};

    const int lrow = lane & 15;
    const int cgrp = lane >> 4;                        // logical chunk 0..3

    for (int k0 = 0; k0 < K; k0 += BK) {
        #pragma unroll
        for (int is = 0; is < BM / 64; ++is)
            GLOAD_LDS16(A + (long long)(row0 + is * 64 + srow) * lda + (k0 + sswz),
                        &Asm[(is * 64 + srow) * BK + skel]);
        #pragma unroll
        for (int is = 0; is < BN / 64; ++is)
            GLOAD_LDS16(BT + (long long)(col0 + is * 64 + srow) * ldb + (k0 + sswz),
                        &Bsm[(is * 64 + srow) * BK + skel]);
        __syncthreads();

        bf16x8 af[MR], bfr[NR];
        #pragma unroll
        for (int mf = 0; mf < MR; ++mf) {
            int row = wr * WM + mf * 16 + lrow;
            int phys = (cgrp ^ ((row >> 1) & 3)) * 8;
            af[mf] = *(const bf16x8*)&Asm[row * BK + phys];
        }
        #pragma unroll
        for (int nf = 0; nf < NR; ++nf) {
            int row = wc * WN + nf * 16 + lrow;
            int phys = (cgrp ^ ((row >> 1) & 3)) * 8;
            bfr[nf] = *(const bf16x8*)&Bsm[row * BK + phys];
        }
        #pragma unroll
        for (int mf = 0; mf < MR; ++mf)
            #pragma unroll
            for (int nf = 0; nf < NR; ++nf)
                acc[mf][nf] = __builtin_amdgcn_mfma_f32_16x16x32_bf16(
                    af[mf], bfr[nf], acc[mf][nf], 0, 0, 0);
        __syncthreads();
    }

    const int crow = (lane >> 4) * 4;
    const int ccol = lane & 15;
    #pragma unroll
    for (int mf = 0; mf < MR; ++mf) {
        int rbase = row0 + wr * WM + mf * 16 + crow;
        #pragma unroll
        for (int nf = 0; nf < NR; ++nf) {
            int c = col0 + wc * WN + nf * 16 + ccol;
            if (c >= N) continue;
            float bv = bias ? bias[c] : 0.f;
            #pragma unroll
            for (int j = 0; j < 4; ++j) {
                int r = rbase + j;
                if (r >= M) continue;
                float v = acc[mf][nf][j] * alpha + bv;
                if (OUT_BF16)
                    ((unsigned short*)Cb)[(long long)r * ldc + c] = f2bf(v);
                else
                    ((float*)Cb)[(long long)r * ldc + c] = v;
            }
        }
    }
}

template<int BM, int BN>
static void gemm_t(bool outBf16,
                   const unsigned short* A, const unsigned short* BT, const float* bias,
                   void* C, int M, int N, int K, int lda, int ldb, int ldc,
                   int batch, long long sA, long long sB, long long sC,
                   float alpha, hipStream_t st)
{
    int gx = (N + BN - 1) / BN, gy = (M + BM - 1) / BM;
    dim3 grid(gx * gy, 1, batch);
    if (outBf16)
        gemm_bf16<BM, BN, true ><<<grid, 256, 0, st>>>(A, BT, bias, C, M, N, K, lda, ldb, ldc, sA, sB, sC, alpha, gx, gy);
    else
        gemm_bf16<BM, BN, false><<<grid, 256, 0, st>>>(A, BT, bias, C, M, N, K, lda, ldb, ldc, sA, sB, sC, alpha, gx, gy);
}

// ---------------------------------------------------------------------------
// split-K reduce + bias + residual(x) + whole-norm stats (r12-proven,
// two-kernel chain: NO inter-block communication, deterministic)
// ---------------------------------------------------------------------------
__global__ void splitk_stats_kernel(const float4* __restrict__ part,
                                    const float4* __restrict__ bias,
                                    const float4* __restrict__ x,
                                    float4* __restrict__ z,
                                    double* __restrict__ dpart,
                                    long long n4, int N4, int nsplit, long long stride4)
{
    __shared__ double rs[256], rs2[256];
    int tid = threadIdx.x;
    long long i = (long long)blockIdx.x * blockDim.x + tid;
    long long gs = (long long)gridDim.x * blockDim.x;
    double s = 0.0, s2 = 0.0;
    for (; i < n4; i += gs) {
        float4 a = part[i];
        for (int sp = 1; sp < nsplit; ++sp) {
            float4 b = part[(long long)sp * stride4 + i];
            a.x += b.x; a.y += b.y; a.z += b.z; a.w += b.w;
        }
        float4 bv = bias[(int)(i % N4)];
        float4 xv = x[i];
        a.x += bv.x + xv.x; a.y += bv.y + xv.y; a.z += bv.z + xv.z; a.w += bv.w + xv.w;
        z[i] = a;
        s  += (double)a.x + (double)a.y + (double)a.z + (double)a.w;
        s2 += (double)a.x * a.x + (double)a.y * a.y + (double)a.z * a.z + (double)a.w * a.w;
    }
    rs[tid] = s; rs2[tid] = s2; __syncthreads();
    for (int k = 128; k > 0; k >>= 1) {
        if (tid < k) { rs[tid] += rs[tid + k]; rs2[tid] += rs2[tid + k]; }
        __syncthreads();
    }
    if (tid == 0) { dpart[2 * blockIdx.x] = rs[0]; dpart[2 * blockIdx.x + 1] = rs2[0]; }
}

__global__ void stats_kernel(const float4* __restrict__ a, const float4* __restrict__ f,
                             double* __restrict__ part, long long n4)
{
    __shared__ double rs[256], rs2[256];
    int tid = threadIdx.x;
    long long i = (long long)blockIdx.x * blockDim.x + tid;
    long long stride = (long long)gridDim.x * blockDim.x;
    double s = 0.0, s2 = 0.0;
    for (; i < n4; i += stride) {
        float4 av = a[i], fv = f[i];
        float z0 = av.x + fv.x, z1 = av.y + fv.y, z2 = av.z + fv.z, z3 = av.w + fv.w;
        s  += (double)z0 + (double)z1 + (double)z2 + (double)z3;
        s2 += (double)z0 * z0 + (double)z1 * z1 + (double)z2 * z2 + (double)z3 * z3;
    }
    rs[tid] = s; rs2[tid] = s2; __syncthreads();
    for (int k = 128; k > 0; k >>= 1) {
        if (tid < k) { rs[tid] += rs[tid + k]; rs2[tid] += rs2[tid + k]; }
        __syncthreads();
    }
    if (tid == 0) { part[2 * blockIdx.x] = rs[0]; part[2 * blockIdx.x + 1] = rs2[0]; }
}

__global__ void finish_stats(const double* __restrict__ part, int npart,
                             float* __restrict__ stats, double n)
{
    __shared__ double rs[256], rs2[256];
    int tid = threadIdx.x;
    double s = 0.0, s2 = 0.0;
    for (int i = tid; i < npart; i += 256) { s += part[2 * i]; s2 += part[2 * i + 1]; }
    rs[tid] = s; rs2[tid] = s2; __syncthreads();
    for (int k = 128; k > 0; k >>= 1) {
        if (tid < k) { rs[tid] += rs[tid + k]; rs2[tid] += rs2[tid + k]; }
        __syncthreads();
    }
    if (tid == 0) {
        double mu  = rs[0] / n;
        double var = rs2[0] / n - mu * mu;
        stats[0] = (float)mu;
        stats[1] = (float)(1.0 / sqrt(var + 1e-6));
    }
}

// norm apply recomputing z = a + f, bf16 out (norm1 -> y1)
__global__ void norm_apply_kernel(const float4* __restrict__ a, const float4* __restrict__ f,
                                  const float4* __restrict__ nw, const float4* __restrict__ nb,
                                  const float* __restrict__ stats, ushort4* __restrict__ out,
                                  long long n4)
{
    float mu = stats[0], rstd = stats[1];
    long long i = (long long)blockIdx.x * blockDim.x + threadIdx.x;
    long long stride = (long long)gridDim.x * blockDim.x;
    for (; i < n4; i += stride) {
        float4 av = a[i], fv = f[i], wv = nw[i], bv = nb[i];
        ushort4 o;
        o.x = f2bf((av.x + fv.x - mu) * rstd * wv.x + bv.x);
        o.y = f2bf((av.y + fv.y - mu) * rstd * wv.y + bv.y);
        o.z = f2bf((av.z + fv.z - mu) * rstd * wv.z + bv.z);
        o.w = f2bf((av.w + fv.w - mu) * rstd * wv.w + bv.w);
        out[i] = o;
    }
}

// norm apply reading z directly (z already includes residual), fp32 out
__global__ void norm_apply_z_kernel(const float4* __restrict__ z,
                                    const float4* __restrict__ nw, const float4* __restrict__ nb,
                                    const float* __restrict__ stats, float4* __restrict__ out,
                                    long long n4)
{
    float mu = stats[0], rstd = stats[1];
    long long i = (long long)blockIdx.x * blockDim.x + threadIdx.x;
    long long stride = (long long)gridDim.x * blockDim.x;
    for (; i < n4; i += stride) {
        float4 zv = z[i], wv = nw[i], bv = nb[i];
        float4 o;
        o.x = (zv.x - mu) * rstd * wv.x + bv.x;
        o.y = (zv.y - mu) * rstd * wv.y + bv.y;
        o.z = (zv.z - mu) * rstd * wv.z + bv.z;
        o.w = (zv.w - mu) * rstd * wv.w + bv.w;
        out[i] = o;
    }
}

// ---------------------------------------------------------------------------
// elementwise cast f32 -> bf16
// ---------------------------------------------------------------------------
__global__ void cast_bf16_kernel(const float4* __restrict__ in,
                                 ushort4* __restrict__ out, long long n4)
{
    long long i = (long long)blockIdx.x * blockDim.x + threadIdx.x;
    long long stride = (long long)gridDim.x * blockDim.x;
    for (; i < n4; i += stride) {
        float4 v = in[i];
        ushort4 o;
        o.x = f2bf(v.x); o.y = f2bf(v.y); o.z = f2bf(v.z); o.w = f2bf(v.w);
        out[i] = o;
    }
}

// concat bias: out = [bq | bk | bv]  (pure data-parallel, no cross-block dep)
__global__ void concat_bias_kernel(const float* __restrict__ bq, const float* __restrict__ bk,
                                   const float* __restrict__ bv, float* __restrict__ out, int D)
{
    int i = blockIdx.x * 256 + threadIdx.x;
    if (i < D) { out[i] = bq[i]; out[D + i] = bk[i]; out[2 * D + i] = bv[i]; }
}

// ---------------------------------------------------------------------------
// transpose + cast: src f32 [R,C] -> dst bf16 [C, Rpad]
// ---------------------------------------------------------------------------
__global__ void transpose_cast_kernel(const float* __restrict__ src,
                                      unsigned short* __restrict__ dst,
                                      int R, int C, int Rpad,
                                      long long sSrc, long long sDst)
{
    __shared__ float t[32][33];
    src += (long long)blockIdx.z * sSrc;
    dst += (long long)blockIdx.z * sDst;
    int r0 = blockIdx.x * 32, c0 = blockIdx.y * 32;
    int tx = threadIdx.x & 31, ty = threadIdx.x >> 5;
    #pragma unroll
    for (int i = 0; i < 32; i += 8) {
        int r = r0 + ty + i, c = c0 + tx;
        t[ty + i][tx] = (r < R && c < C) ? src[(long long)r * C + c] : 0.f;
    }
    __syncthreads();
    #pragma unroll
    for (int i = 0; i < 32; i += 8) {
        int c = c0 + ty + i, r = r0 + tx;
        if (c < C && r < Rpad)
            dst[(long long)c * Rpad + r] = f2bf(t[tx][ty + i]);
    }
}

// three same-shape square transposes in one launch (QKV weights), z selects
__global__ void transpose_cast3_kernel(const float* __restrict__ s0,
                                       const float* __restrict__ s1,
                                       const float* __restrict__ s2,
                                       unsigned short* __restrict__ dst, int D)
{
    __shared__ float t[32][33];
    const float* src = blockIdx.z == 0 ? s0 : (blockIdx.z == 1 ? s1 : s2);
    dst += (long long)blockIdx.z * D * D;
    int r0 = blockIdx.x * 32, c0 = blockIdx.y * 32;
    int tx = threadIdx.x & 31, ty = threadIdx.x >> 5;
    #pragma unroll
    for (int i = 0; i < 32; i += 8)
        t[ty + i][tx] = src[(long long)(r0 + ty + i) * D + (c0 + tx)];
    __syncthreads();
    #pragma unroll
    for (int i = 0; i < 32; i += 8)
        dst[(long long)(c0 + ty + i) * D + (r0 + tx)] = f2bf(t[tx][ty + i]);
}

// transpose bf16 [R,C] (row stride ldS) -> bf16 [C, Rpad]
__global__ void transpose_bf16_kernel(const unsigned short* __restrict__ src,
                                      unsigned short* __restrict__ dst,
                                      int R, int C, int Rpad, int ldS,
                                      long long sSrc, long long sDst)
{
    __shared__ unsigned short t[32][33];
    src += (long long)blockIdx.z * sSrc;
    dst += (long long)blockIdx.z * sDst;
    int r0 = blockIdx.x * 32, c0 = blockIdx.y * 32;
    int tx = threadIdx.x & 31, ty = threadIdx.x >> 5;
    #pragma unroll
    for (int i = 0; i < 32; i += 8) {
        int r = r0 + ty + i, c = c0 + tx;
        t[ty + i][tx] = (r < R && c < C) ? src[(long long)r * ldS + c] : (unsigned short)0;
    }
    __syncthreads();
    #pragma unroll
    for (int i = 0; i < 32; i += 8) {
        int c = c0 + ty + i, r = r0 + tx;
        if (c < C && r < Rpad)
            dst[(long long)c * Rpad + r] = t[tx][ty + i];
    }
}

// ---------------------------------------------------------------------------
// Ktot two-stage deterministic reduction over s (bf16 input, strided ld)
// ---------------------------------------------------------------------------
#define KTOT_NCH 16
__global__ void ktot_partial_bf16(const unsigned short* __restrict__ k,
                                  float* __restrict__ part,
                                  int B, int S, int D, int ld)
{
    int bch = blockIdx.x;
    int b  = bch / KTOT_NCH;
    int ch = bch % KTOT_NCH;
    int d  = blockIdx.y * 256 + threadIdx.x;
    if (d >= D) return;
    int len = (S + KTOT_NCH - 1) / KTOT_NCH;
    int lo = ch * len;
    int hi = lo + len < S ? lo + len : S;
    const unsigned short* kp = k + ((long long)b * S + lo) * ld + d;
    float s = 0.f;
    for (int t = lo; t < hi; ++t, kp += ld) s += bf2f(*kp);
    part[(long long)bch * D + d] = s;
}

__global__ void ktot_finish_kernel(const float* __restrict__ part,
                                   float* __restrict__ ktot, int B, int D)
{
    int idx = blockIdx.x * blockDim.x + threadIdx.x;
    if (idx >= B * D) return;
    int b = idx / D, d = idx % D;
    float s = 0.f;
    #pragma unroll
    for (int ch = 0; ch < KTOT_NCH; ++ch)
        s += part[((long long)b * KTOT_NCH + ch) * D + d];
    ktot[idx] = s;
}

// ---------------------------------------------------------------------------
// kk[b,s,d] = (Ktot[b,d] + (e-1)*window_sum) / Z_s  from bf16 k (stride ld)
// ---------------------------------------------------------------------------
__global__ void kk_bf16_kernel(const unsigned short* __restrict__ k,
                               const float* __restrict__ ktot,
                               unsigned short* __restrict__ kk,
                               int B, int S, int D, int ld)
{
    long long idx = (long long)blockIdx.x * blockDim.x + threadIdx.x;
    int D4 = D >> 2;
    long long n4 = (long long)B * S * D4;
    if (idx >= n4) return;
    int d4 = (int)(idx % D4);
    long long bs = idx / D4;
    int s = (int)(bs % S);
    int b = (int)(bs / S);
    int lo = s - 2 > 0 ? s - 2 : 0;
    int hi = s + 2 < S - 1 ? s + 2 : S - 1;
    int c = hi - lo + 1;
    const float E = 2.718281828459045f;
    float Zinv = 1.f / ((float)(S - c) + E * (float)c);

    float w0 = 0.f, w1 = 0.f, w2 = 0.f, w3 = 0.f;
    const unsigned short* kp = k + ((long long)b * S + lo) * ld + d4 * 4;
    for (int t = lo; t <= hi; ++t, kp += ld) {
        ushort4 kv = *(const ushort4*)kp;
        w0 += bf2f(kv.x); w1 += bf2f(kv.y); w2 += bf2f(kv.z); w3 += bf2f(kv.w);
    }
    float4 tot = *((const float4*)(ktot + b * D) + d4);
    ushort4 o;
    o.x = f2bf((tot.x + (E - 1.f) * w0) * Zinv);
    o.y = f2bf((tot.y + (E - 1.f) * w1) * Zinv);
    o.z = f2bf((tot.z + (E - 1.f) * w2) * Zinv);
    o.w = f2bf((tot.w + (E - 1.f) * w3) * Zinv);
    ((ushort4*)(kk + ((long long)b * S + s) * D))[d4] = o;
}

// ---------------------------------------------------------------------------
// row softmax: fp32 scores [rows][Spad] -> bf16 P, pads = 0.
// Register-cached: one read pass, exp computed once, one write pass.
// Requires S <= 512 and Spad <= 512 (text 512/512, image 196/224).
// ---------------------------------------------------------------------------
__global__ void softmax_rows_bf16(const float* __restrict__ sc,
                                  unsigned short* __restrict__ P, int S, int Spad)
{
    long long row = blockIdx.x;
    const float* p = sc + row * (long long)Spad;
    unsigned short* o = P + row * (long long)Spad;
    int tid = threadIdx.x;
    __shared__ float red[256];

    float v0 = (tid < S)       ? p[tid]       : -INFINITY;
    float v1 = (tid + 256 < S) ? p[tid + 256] : -INFINITY;

    float m = fmaxf(v0, v1);
    red[tid] = m; __syncthreads();
    for (int s = 128; s > 0; s >>= 1) {
        if (tid < s) red[tid] = fmaxf(red[tid], red[tid + s]);
        __syncthreads();
    }
    m = red[0];
    __syncthreads();

    float e0 = (tid < S)       ? __expf(v0 - m) : 0.f;
    float e1 = (tid + 256 < S) ? __expf(v1 - m) : 0.f;
    red[tid] = e0 + e1; __syncthreads();
    for (int s = 128; s > 0; s >>= 1) {
        if (tid < s) red[tid] += red[tid + s];
        __syncthreads();
    }
    float inv = 1.f / red[0];

    if (tid < Spad)       o[tid]       = (tid < S)       ? f2bf(e0 * inv) : (unsigned short)0;
    if (tid + 256 < Spad) o[tid + 256] = (tid + 256 < S) ? f2bf(e1 * inv) : (unsigned short)0;
}

// ---------------------------------------------------------------------------
// host-side orchestration
// ---------------------------------------------------------------------------
struct Bufs {
    unsigned short *xb, *qkv, *kkb, *vT, *P, *h, *WqkvT, *W1T, *W2T;
    float *f32buf, *bqkv, *ktot, *ktot_part, *stats;
    double *part;
};

static void run_branch(const float* x, const float* const* w, bool big,
                       float* out, int B, int S, int D, const Bufs& wsb, hipStream_t st)
{
    const float *Wq = w[0], *bq = w[1], *Wk = w[2], *bk = w[3], *Wv = w[4], *bv = w[5];
    const float *W1 = w[6], *b1 = w[7], *W2 = w[8], *b2 = w[9], *nw = w[10], *nb = w[11];

    const int Spad = (S + 31) & ~31;
    const long long M = (long long)B * S;
    const long long n = M * D;
    const long long n4 = n / 4;
    const float inv_sqrt_d = (float)(1.0 / sqrt((double)D));
    const int D3 = 3 * D, D4 = 4 * D;

    unsigned short* y1b = wsb.kkb;           // alias: kkb dead after scores GEMM
    float* scores = (float*)wsb.h;           // alias: h free until FFN1
    float* splitbuf = (float*)wsb.qkv;       // alias: qkv+kkb+vT dead during FFN2

    // casts: x -> xb ; weights -> transposed bf16 (QKV concat), bias concat
    cast_bf16_kernel<<<1024, 256, 0, st>>>((const float4*)x, (ushort4*)wsb.xb, n4);
    transpose_cast3_kernel<<<dim3(D / 32, D / 32, 3), 256, 0, st>>>(Wq, Wk, Wv, wsb.WqkvT, D);
    transpose_cast_kernel<<<dim3((D + 31) / 32, (D4 + 31) / 32, 1), 256, 0, st>>>(W1, wsb.W1T, D, D4, D, 0, 0);
    transpose_cast_kernel<<<dim3((D4 + 31) / 32, (D + 31) / 32, 1), 256, 0, st>>>(W2, wsb.W2T, D4, D, D4, 0, 0);
    concat_bias_kernel<<<(D + 255) / 256, 256, 0, st>>>(bq, bk, bv, wsb.bqkv, D);

    // fused QKV: [M,3D] bf16 (gemm4 128x128)
    gemm4_t<4, 2>(true, false, wsb.xb, wsb.WqkvT, wsb.bqkv, wsb.qkv,
                  (int)M, D3, D, D, D, D3, 1, 0, 0, 0, 1.f, st);

    // kk = softmax(band mask) @ k  (analytic, bf16 k at column offset D)
    const unsigned short* kcol = wsb.qkv + D;
    ktot_partial_bf16<<<dim3(B * KTOT_NCH, (D + 255) / 256), 256, 0, st>>>(kcol, wsb.ktot_part, B, S, D, D3);
    ktot_finish_kernel<<<(B * D + 255) / 256, 256, 0, st>>>(wsb.ktot_part, wsb.ktot, B, D);
    kk_bf16_kernel<<<(int)((n4 + 255) / 256), 256, 0, st>>>(kcol, wsb.ktot, wsb.kkb, B, S, D, D3);

    // vT bf16 [B][D][Spad]  (v at column offset 2D)
    transpose_bf16_kernel<<<dim3((Spad + 31) / 32, (D + 31) / 32, B), 256, 0, st>>>(
        wsb.qkv + 2 * D, wsb.vT, S, D, Spad, D3, (long long)S * D3, (long long)D * Spad);

    // scores = q @ kk^T / sqrt(D)
    gemm_t<64, 64>(false, wsb.qkv, wsb.kkb, nullptr, scores, S, S, D, D3, D, Spad,
                   B, (long long)S * D3, (long long)S * D, (long long)S * Spad, inv_sqrt_d, st);
    softmax_rows_bf16<<<(int)M, 256, 0, st>>>(scores, wsb.P, S, Spad);

    // attn = P @ v -> f32buf
    gemm_t<128, 64>(false, wsb.P, wsb.vT, nullptr, wsb.f32buf, S, D, Spad, Spad, Spad, D,
                    B, (long long)S * Spad, (long long)D * Spad, (long long)S * D, 1.f, st);

    // norm1: y1 = whole_norm(attn + x) -> bf16 (into kkb region)
    stats_kernel<<<1024, 256, 0, st>>>((const float4*)wsb.f32buf, (const float4*)x, wsb.part, n4);
    finish_stats<<<1, 256, 0, st>>>(wsb.part, 1024, wsb.stats, (double)n);
    norm_apply_kernel<<<2048, 256, 0, st>>>((const float4*)wsb.f32buf, (const float4*)x,
        (const float4*)nw, (const float4*)nb, wsb.stats, (ushort4*)y1b, n4);

    // FFN1 -> h (bf16, relu), gemm4 128x128
    gemm4_t<4, 2>(true, true, y1b, wsb.W1T, b1, wsb.h, (int)M, D4, D, D, D, D4, 1, 0, 0, 0, 1.f, st);

    // FFN2 split-K -> partials (fp32), reduce+bias+residual+stats, finish, apply
    {
        int nsplit = big ? 2 : 8;
        int Ksp = D4 / nsplit;
        gemm4_t<4, 2>(false, false, wsb.h, wsb.W2T, nullptr, splitbuf,
                      (int)M, D, Ksp, D4, D4, D,
                      nsplit, Ksp, Ksp, M * D, 1.f, st);
        splitk_stats_kernel<<<1024, 256, 0, st>>>((const float4*)splitbuf, (const float4*)b2,
                                                  (const float4*)x, (float4*)wsb.f32buf,
                                                  wsb.part, n4, D / 4, nsplit, n4);
        finish_stats<<<1, 256, 0, st>>>(wsb.part, 1024, wsb.stats, (double)n);
        norm_apply_z_kernel<<<2048, 256, 0, st>>>((const float4*)wsb.f32buf,
            (const float4*)nw, (const float4*)nb, wsb.stats, (float4*)out, n4);
    }
}

extern "C" void kernel_launch(void* const* d_in, const int* in_sizes, int n_in,
                              void* d_out, int out_size, void* d_ws, size_t ws_size,
                              hipStream_t stream)
{
    const float* text  = (const float*)d_in[0];
    const float* image = (const float*)d_in[1];
    const float* tw[12];
    const float* iw[12];
    for (int i = 0; i < 12; ++i) tw[i] = (const float*)d_in[2 + i];
    for (int i = 0; i < 12; ++i) iw[i] = (const float*)d_in[14 + i];

    float* out_text = (float*)d_out;                 // [8,512,1024]
    float* out_img  = out_text + 8LL * 512 * 1024;   // [8,196,768]

    // workspace layout (text-branch sizes; image reuses)
    char* p = (char*)d_ws;
    auto alloc = [&](long long bytes) {
        char* r = p;
        p += (bytes + 255) & ~255LL;
        return r;
    };
    const long long MD  = 4096LL * 1024;    // B*S*D
    const long long BDS = 8LL * 1024 * 512; // B*D*Spad
    const long long SS  = 8LL * 512 * 512;  // B*S*Spad
    Bufs b;
    b.xb      = (unsigned short*)alloc(MD * 2);          // 8 MB
    b.qkv     = (unsigned short*)alloc(MD * 3 * 2);      // 24 MB (splitbuf lo)
    b.kkb     = (unsigned short*)alloc(MD * 2);          // 8 MB (y1b, splitbuf mid)
    b.vT      = (unsigned short*)alloc(BDS * 2);         // 8 MB (splitbuf hi, image)
    b.P       = (unsigned short*)alloc(SS * 2);          // 4 MB
    b.h       = (unsigned short*)alloc(MD * 4 * 2);      // 32 MB (also scores)
    b.WqkvT   = (unsigned short*)alloc(3LL * 1024 * 1024 * 2);  // 6 MB
    b.W1T     = (unsigned short*)alloc(4096LL * 1024 * 2);      // 8 MB
    b.W2T     = (unsigned short*)alloc(4096LL * 1024 * 2);      // 8 MB
    b.f32buf  = (float*)alloc(MD * 4);                   // 16 MB
    b.bqkv    = (float*)alloc(3LL * 1024 * 4);
    b.ktot    = (float*)alloc(8192LL * 4);
    b.ktot_part = (float*)alloc(8192LL * KTOT_NCH * 4);
    b.part    = (double*)alloc(2048LL * 8);
    b.stats   = (float*)alloc(256);

    run_branch(text,  tw, true,  out_text, 8, 512, 1024, b, stream);
    run_branch(image, iw, false, out_img,  8, 196, 768,  b, stream);
}